// Round 3
// baseline (378.058 us; speedup 1.0000x reference)
//
#include <hip/hip_runtime.h>
#include <math.h>

#define N_NODES 100000
#define N_EDGES 800000
#define NEG_SLOPE 0.2f
#define GEMM_BLOCKS 782            // ceil(100000/128)
#define HIST_BLOCKS 3125           // 800000/256
#define CSR_STRIDE 16              // padded CSR; Poisson(8) => ~600 of 800k edges overflow
#define OVF_CAP 16384

typedef __attribute__((ext_vector_type(8))) short short8;
typedef __attribute__((ext_vector_type(4))) float floatx4;

__device__ __forceinline__ float lrelu(float x) { return x > 0.f ? x : NEG_SLOPE * x; }

__device__ __forceinline__ unsigned bf16_rne(float f) {
    unsigned u = __float_as_uint(f);
    return (u + 0x7fffu + ((u >> 16) & 1u)) >> 16;
}
__device__ __forceinline__ unsigned bfpack(float lo, float hi) {
    return bf16_rne(lo) | (bf16_rne(hi) << 16);
}
__device__ __forceinline__ float bflo(unsigned p) { return __uint_as_float(p << 16); }
__device__ __forceinline__ float bfhi(unsigned p) { return __uint_as_float(p & 0xffff0000u); }

// ---------------- K1: W^T (0..127) + E (128..129) + zero deg (130..227) + zero ovf_cnt (228) ----------------
__global__ __launch_bounds__(256) void k_prep0(const float* __restrict__ W1,
                                               const float* __restrict__ al1,
                                               const float* __restrict__ ar1,
                                               const float* __restrict__ W2,
                                               const float* __restrict__ al2,
                                               const float* __restrict__ ar2,
                                               unsigned short* __restrict__ wt1,
                                               unsigned short* __restrict__ wt2,
                                               unsigned short* __restrict__ et1,
                                               unsigned short* __restrict__ et2,
                                               int* __restrict__ deg,
                                               int* __restrict__ ovf_cnt) {
    int b = blockIdx.x, tid = threadIdx.x;
    if (b < 128) {
        int t2 = b * 256 + tid;                   // 0..32767
        const float* W = (t2 < 16384) ? W1 : W2;
        unsigned short* wt = (t2 < 16384) ? wt1 : wt2;
        int t = t2 & 16383;
        int n = t >> 7, k = t & 127;
        wt[t] = (unsigned short)bf16_rne(W[k * 128 + n]);
    } else if (b < 130) {
        // E[n][k]: n<4 -> (W al)_head n ; 4<=n<8 -> (W ar)_head n-4 ; else 0
        const float* W = (b == 128) ? W1 : W2;
        const float* al = (b == 128) ? al1 : al2;
        const float* ar = (b == 128) ? ar1 : ar2;
        unsigned short* et = (b == 128) ? et1 : et2;
        for (int o = tid * 8; o < tid * 8 + 8; o++) {   // 2048 outputs
            int n = o >> 7, k = o & 127;
            float sacc = 0.f;
            if (n < 8) {
                const float* a = (n < 4) ? al : ar;
                int hh = n & 3;
                #pragma unroll 8
                for (int c = 0; c < 32; c++)
                    sacc += W[k * 128 + hh * 32 + c] * a[hh * 32 + c];
            }
            et[n * 128 + k] = (unsigned short)bf16_rne(sacc);
        }
    } else if (b < 228) {
        int i = (b - 130) * 1024 + tid * 4;
        if (i + 3 < N_NODES) *(int4*)&deg[i] = make_int4(0, 0, 0, 0);
        else { for (int j = i; j < N_NODES; j++) if (j >= 0) deg[j] = 0; }
    } else {
        if (tid == 0) *ovf_cnt = 0;
    }
}

// ---------------- shared GEMM tile body (MFMA, direct-global A frags, el/er via MFMA) ----------------
__device__ __forceinline__ void gemm_tile(int base, const void* __restrict__ Xv,
                                          const unsigned short* __restrict__ wt,
                                          const unsigned short* __restrict__ et,
                                          unsigned* __restrict__ Hb,
                                          float* __restrict__ EL,
                                          float* __restrict__ ER,
                                          int src_bf16,
                                          unsigned short* wsh,   // [128*128]
                                          unsigned short* esh) { // [16*136]
    int tid = threadIdx.x;
    int w = tid >> 6, lane = tid & 63;
    int q = lane >> 4, nl = lane & 15;

    const uint4* wt4 = (const uint4*)wt;
    #pragma unroll
    for (int i = 0; i < 8; i++) {
        int idx = tid + i * 256;                // 0..2047 chunks of 8 shorts
        int rn = idx >> 4, c8 = idx & 15;
        int kc = c8 >> 2, qq = c8 & 3;
        int slot = rn * 128 + ((kc ^ ((rn >> 2) & 3)) * 4 + (qq ^ (rn & 3))) * 8;
        *(uint4*)&wsh[slot] = wt4[idx];
    }
    {
        const uint4* et4 = (const uint4*)et;
        int rn = tid >> 4, c8 = tid & 15;
        *(uint4*)&esh[rn * 136 + c8 * 8] = et4[tid];
    }

    short8 afr[2][4];
    int row0 = base + w * 32 + nl;
    if (!src_bf16) {
        const float4* X4 = (const float4*)Xv;
        #pragma unroll
        for (int rt = 0; rt < 2; rt++) {
            int rr = row0 + rt * 16; if (rr > N_NODES - 1) rr = N_NODES - 1;
            const float4* px = X4 + (size_t)rr * 32 + q * 2;
            #pragma unroll
            for (int kc = 0; kc < 4; kc++) {
                float4 u = px[kc * 8], v = px[kc * 8 + 1];
                short8 f;
                f[0] = (short)bf16_rne(u.x); f[1] = (short)bf16_rne(u.y);
                f[2] = (short)bf16_rne(u.z); f[3] = (short)bf16_rne(u.w);
                f[4] = (short)bf16_rne(v.x); f[5] = (short)bf16_rne(v.y);
                f[6] = (short)bf16_rne(v.z); f[7] = (short)bf16_rne(v.w);
                afr[rt][kc] = f;
            }
        }
    } else {
        const unsigned short* Xb = (const unsigned short*)Xv;
        #pragma unroll
        for (int rt = 0; rt < 2; rt++) {
            int rr = row0 + rt * 16; if (rr > N_NODES - 1) rr = N_NODES - 1;
            #pragma unroll
            for (int kc = 0; kc < 4; kc++)
                afr[rt][kc] = *(const short8*)(Xb + (size_t)rr * 128 + kc * 32 + q * 8);
        }
    }

    floatx4 acc[2][8];
    floatx4 acc_e[2];
    #pragma unroll
    for (int rt = 0; rt < 2; rt++) {
        acc_e[rt] = (floatx4){0.f, 0.f, 0.f, 0.f};
        #pragma unroll
        for (int ct = 0; ct < 8; ct++)
            acc[rt][ct] = (floatx4){0.f, 0.f, 0.f, 0.f};
    }

    __syncthreads();

    int sw_hi = (nl >> 2) & 3, sw_lo = nl & 3;
    #pragma unroll
    for (int ct = 0; ct < 8; ct++) {
        int rbase = (ct * 16 + nl) * 128;
        #pragma unroll
        for (int kc = 0; kc < 4; kc++) {
            short8 b = *(const short8*)&wsh[rbase + ((kc ^ sw_hi) * 4 + (q ^ sw_lo)) * 8];
            acc[0][ct] = __builtin_amdgcn_mfma_f32_16x16x32_bf16(afr[0][kc], b, acc[0][ct], 0, 0, 0);
            acc[1][ct] = __builtin_amdgcn_mfma_f32_16x16x32_bf16(afr[1][kc], b, acc[1][ct], 0, 0, 0);
        }
    }
    #pragma unroll
    for (int kc = 0; kc < 4; kc++) {
        short8 e8 = *(const short8*)&esh[nl * 136 + (kc * 4 + q) * 8];
        acc_e[0] = __builtin_amdgcn_mfma_f32_16x16x32_bf16(afr[0][kc], e8, acc_e[0], 0, 0, 0);
        acc_e[1] = __builtin_amdgcn_mfma_f32_16x16x32_bf16(afr[1][kc], e8, acc_e[1], 0, 0, 0);
    }

    #pragma unroll
    for (int rt = 0; rt < 2; rt++) {
        #pragma unroll
        for (int r = 0; r < 4; r++) {
            int row = base + w * 32 + rt * 16 + q * 4 + r;
            bool valid = row < N_NODES;
            unsigned* hrow = Hb + (size_t)row * 64;
            #pragma unroll
            for (int ct = 0; ct < 8; ct++) {
                float vlo = acc[rt][ct][r];
                float vhi = __shfl_down(vlo, 1);
                if (valid && !(nl & 1)) hrow[ct * 8 + (nl >> 1)] = bfpack(vlo, vhi);
            }
            if (valid && nl < 8) {
                float v = acc_e[rt][r];
                if (nl < 4) EL[row * 4 + nl] = v;
                else        ER[row * 4 + (nl & 3)] = v;
            }
        }
    }
}

// ---------------- K2: gemm layer-1 (blocks 0..781) + fused hist+scatter (782..3906) ----------------
// atomicAdd's return value IS the CSR slot; rare deg>16 edges spill to a tiny overflow list.
__global__ __launch_bounds__(256) void k_gemm_hist(const float* __restrict__ feat,
                                                   const unsigned short* __restrict__ wt1,
                                                   const unsigned short* __restrict__ et1,
                                                   unsigned* __restrict__ Hb,
                                                   float* __restrict__ EL,
                                                   float* __restrict__ ER,
                                                   const int* __restrict__ src,
                                                   const int* __restrict__ dst,
                                                   int* __restrict__ deg,
                                                   int* __restrict__ csr,
                                                   int2* __restrict__ ovf,
                                                   int* __restrict__ ovf_cnt) {
    __shared__ unsigned short wsh[128 * 128];
    __shared__ unsigned short esh[16 * 136];
    int b = blockIdx.x;
    if (b < GEMM_BLOCKS) {
        gemm_tile(b * 128, feat, wt1, et1, Hb, EL, ER, 0, wsh, esh);
    } else {
        int e = (b - GEMM_BLOCKS) * 256 + threadIdx.x;
        if (e < N_EDGES) {
            int d = dst[e];
            int s = src[e];
            int c = atomicAdd(&deg[d], 1);
            if (c < CSR_STRIDE) {
                csr[d * CSR_STRIDE + c] = s;
            } else {
                int p = atomicAdd(ovf_cnt, 1);
                if (p < OVF_CAP) ovf[p] = make_int2(d, s);
            }
        }
    }
}

// ---------------- K4: plain gemm (layer 2) ----------------
__global__ __launch_bounds__(256) void k_gemm(const void* __restrict__ Xv,
                                              const unsigned short* __restrict__ wt,
                                              const unsigned short* __restrict__ et,
                                              unsigned* __restrict__ Hb,
                                              float* __restrict__ EL,
                                              float* __restrict__ ER,
                                              int src_bf16) {
    __shared__ unsigned short wsh[128 * 128];
    __shared__ unsigned short esh[16 * 136];
    gemm_tile(blockIdx.x * 128, Xv, wt, et, Hb, EL, ER, src_bf16, wsh, esh);
}

// ---------------- K3/K5: gather (one node per 16-lane group, 8-edge batches, padded CSR + ovf) ----------------
__global__ __launch_bounds__(256) void k_gather(const int* __restrict__ deg,
                                                const int* __restrict__ csr,
                                                const int2* __restrict__ ovf,
                                                const int* __restrict__ ovf_cnt,
                                                const float* __restrict__ EL,
                                                const float* __restrict__ ER,
                                                const unsigned* __restrict__ Hb,
                                                const float* __restrict__ bias,
                                                void* __restrict__ out,
                                                int final_layer) {
    int wid = (blockIdx.x * blockDim.x + threadIdx.x) >> 6;
    int lane = threadIdx.x & 63;
    int l = lane & 15;                 // lane within group: covers channels l*8 .. l*8+7
    int h = l >> 2;                    // head of those channels
    int n = wid * 4 + (lane >> 4);     // one node per 16-lane group
    if (n >= N_NODES) return;

    int d = deg[n];
    int dmain = d < CSR_STRIDE ? d : CSR_STRIDE;
    float erh = ER[n * 4 + h];

    float bv[8];
    #pragma unroll
    for (int c = 0; c < 8; c++) bv[c] = bias[l * 8 + c];

    float acc[8];
    #pragma unroll
    for (int c = 0; c < 8; c++) acc[c] = 0.f;
    float sa = 0.f;

    const int* cb = csr + n * CSR_STRIDE;
    for (int j = 0; j < dmain; j += 8) {
        // batch-load up to 8 edge indices (independent, issue together)
        int ii[8];
        #pragma unroll
        for (int k = 0; k < 8; k++) ii[k] = (j + k < dmain) ? cb[j + k] : -1;
        // batch-load 8 Hb rows + 8 EL values (independent, issue together)
        uint4 P[8];
        float W[8];
        #pragma unroll
        for (int k = 0; k < 8; k++) {
            if (ii[k] >= 0) {
                P[k] = *(const uint4*)(Hb + (size_t)ii[k] * 64 + l * 4);
                W[k] = __expf(lrelu(EL[ii[k] * 4 + h] + erh));
            } else {
                P[k] = make_uint4(0u, 0u, 0u, 0u);
                W[k] = 0.f;
            }
        }
        #pragma unroll
        for (int k = 0; k < 8; k++) {
            sa += W[k];
            acc[0] = fmaf(bflo(P[k].x), W[k], acc[0]); acc[1] = fmaf(bfhi(P[k].x), W[k], acc[1]);
            acc[2] = fmaf(bflo(P[k].y), W[k], acc[2]); acc[3] = fmaf(bfhi(P[k].y), W[k], acc[3]);
            acc[4] = fmaf(bflo(P[k].z), W[k], acc[4]); acc[5] = fmaf(bfhi(P[k].z), W[k], acc[5]);
            acc[6] = fmaf(bflo(P[k].w), W[k], acc[6]); acc[7] = fmaf(bfhi(P[k].w), W[k], acc[7]);
        }
    }

    // rare overflow edges (deg > CSR_STRIDE): scan the tiny global overflow list
    if (d > CSR_STRIDE) {
        int m = *ovf_cnt;
        if (m > OVF_CAP) m = OVF_CAP;
        for (int o = 0; o < m; o++) {
            int2 pr = ovf[o];
            if (pr.x == n) {
                int s0 = pr.y;
                uint4 P = *(const uint4*)(Hb + (size_t)s0 * 64 + l * 4);
                float W = __expf(lrelu(EL[s0 * 4 + h] + erh));
                sa += W;
                acc[0] = fmaf(bflo(P.x), W, acc[0]); acc[1] = fmaf(bfhi(P.x), W, acc[1]);
                acc[2] = fmaf(bflo(P.y), W, acc[2]); acc[3] = fmaf(bfhi(P.y), W, acc[3]);
                acc[4] = fmaf(bflo(P.z), W, acc[4]); acc[5] = fmaf(bfhi(P.z), W, acc[5]);
                acc[6] = fmaf(bflo(P.w), W, acc[6]); acc[7] = fmaf(bfhi(P.w), W, acc[7]);
            }
        }
    }

    float inv = (d > 0) ? 1.f / sa : 0.f;
    float r[8];
    #pragma unroll
    for (int c = 0; c < 8; c++) r[c] = acc[c] * inv + bv[c];

    if (!final_layer) {
        uint4 pk;
        pk.x = bfpack(fmaxf(r[0], 0.f), fmaxf(r[1], 0.f));
        pk.y = bfpack(fmaxf(r[2], 0.f), fmaxf(r[3], 0.f));
        pk.z = bfpack(fmaxf(r[4], 0.f), fmaxf(r[5], 0.f));
        pk.w = bfpack(fmaxf(r[6], 0.f), fmaxf(r[7], 0.f));
        *(uint4*)((unsigned*)out + (size_t)n * 64 + l * 4) = pk;
    } else {
        // mean over 4 heads: lanes l, l^4, l^8 hold the same within-head offsets
        #pragma unroll
        for (int c = 0; c < 8; c++) {
            r[c] += __shfl_xor(r[c], 4);
            r[c] += __shfl_xor(r[c], 8);
        }
        if (l < 4) {
            float* po = (float*)out + (size_t)n * 32 + l * 8;
            *(float4*)po = make_float4(0.25f * r[0], 0.25f * r[1], 0.25f * r[2], 0.25f * r[3]);
            *(float4*)(po + 4) = make_float4(0.25f * r[4], 0.25f * r[5], 0.25f * r[6], 0.25f * r[7]);
        }
    }
}

extern "C" void kernel_launch(void* const* d_in, const int* in_sizes, int n_in,
                              void* d_out, int out_size, void* d_ws, size_t ws_size,
                              hipStream_t stream) {
    const float* feat = (const float*)d_in[0];
    const int* src = (const int*)d_in[1];
    const int* dst = (const int*)d_in[2];
    const float* W1 = (const float*)d_in[3];
    const float* al1 = (const float*)d_in[4];
    const float* ar1 = (const float*)d_in[5];
    const float* b1 = (const float*)d_in[6];
    const float* W2 = (const float*)d_in[7];
    const float* al2 = (const float*)d_in[8];
    const float* ar2 = (const float*)d_in[9];
    const float* b2 = (const float*)d_in[10];
    float* out = (float*)d_out;

    char* ws = (char*)d_ws;
    size_t off = 0;
    auto alloc = [&](size_t bytes) {
        void* p = ws + off;
        off += (bytes + 255) & ~(size_t)255;
        return p;
    };
    int* deg = (int*)alloc((size_t)N_NODES * 4);
    int* ovf_cnt = (int*)alloc(256);
    int* csr = (int*)alloc((size_t)N_NODES * CSR_STRIDE * 4);      // 6.4 MB padded CSR
    int2* ovf = (int2*)alloc((size_t)OVF_CAP * 8);                 // 128 KB overflow list
    unsigned* Hb = (unsigned*)alloc((size_t)N_NODES * 64 * 4);     // bf16 H pairs
    float* el = (float*)alloc((size_t)N_NODES * 4 * 4);
    float* er = (float*)alloc((size_t)N_NODES * 4 * 4);
    unsigned* out1b = (unsigned*)alloc((size_t)N_NODES * 64 * 4);  // bf16 relu(out1)
    unsigned short* wt1 = (unsigned short*)alloc(128 * 128 * 2);
    unsigned short* wt2 = (unsigned short*)alloc(128 * 128 * 2);
    unsigned short* et1 = (unsigned short*)alloc(16 * 128 * 2);
    unsigned short* et2 = (unsigned short*)alloc(16 * 128 * 2);

    int gat_blocks = (N_NODES + 15) / 16;

    // K1: wprep + E + zero deg/ovf_cnt
    k_prep0<<<229, 256, 0, stream>>>(W1, al1, ar1, W2, al2, ar2,
                                     wt1, wt2, et1, et2, deg, ovf_cnt);
    // K2: layer-1 GEMM co-scheduled with fused hist+scatter (padded CSR, no scan/scatter pass)
    k_gemm_hist<<<GEMM_BLOCKS + HIST_BLOCKS, 256, 0, stream>>>(feat, wt1, et1, Hb, el, er,
                                                               src, dst, deg, csr, ovf, ovf_cnt);
    // K3: gather layer 1
    k_gather<<<gat_blocks, 256, 0, stream>>>(deg, csr, ovf, ovf_cnt, el, er, Hb, b1, out1b, 0);
    // K4: gemm layer 2   K5: gather layer 2
    k_gemm<<<GEMM_BLOCKS, 256, 0, stream>>>(out1b, wt2, et2, Hb, el, er, 1);
    k_gather<<<gat_blocks, 256, 0, stream>>>(deg, csr, ovf, ovf_cnt, el, er, Hb, b2, out, 1);
}

// Round 4
// 324.311 us; speedup vs baseline: 1.1657x; 1.1657x over previous
//
#include <hip/hip_runtime.h>
#include <math.h>

#define N_NODES 100000
#define N_EDGES 800000
#define NEG_SLOPE 0.2f
#define GEMM_BLOCKS 782            // ceil(100000/128)
#define HIST_BLOCKS 3125           // 800000/256

typedef __attribute__((ext_vector_type(8))) short short8;
typedef __attribute__((ext_vector_type(4))) float floatx4;

__device__ __forceinline__ float lrelu(float x) { return x > 0.f ? x : NEG_SLOPE * x; }

__device__ __forceinline__ unsigned bf16_rne(float f) {
    unsigned u = __float_as_uint(f);
    return (u + 0x7fffu + ((u >> 16) & 1u)) >> 16;
}
__device__ __forceinline__ unsigned bfpack(float lo, float hi) {
    return bf16_rne(lo) | (bf16_rne(hi) << 16);
}
__device__ __forceinline__ float bflo(unsigned p) { return __uint_as_float(p << 16); }
__device__ __forceinline__ float bfhi(unsigned p) { return __uint_as_float(p & 0xffff0000u); }

// ---------------- K1: W^T (0..127) + E (128..129) + histogram (130..3254) ----------------
// deg/done are zeroed by a hipMemsetAsync before this kernel; hist is fire-and-forget.
__global__ __launch_bounds__(256) void k_prep_hist(const float* __restrict__ W1,
                                                   const float* __restrict__ al1,
                                                   const float* __restrict__ ar1,
                                                   const float* __restrict__ W2,
                                                   const float* __restrict__ al2,
                                                   const float* __restrict__ ar2,
                                                   unsigned short* __restrict__ wt1,
                                                   unsigned short* __restrict__ wt2,
                                                   unsigned short* __restrict__ et1,
                                                   unsigned short* __restrict__ et2,
                                                   const int* __restrict__ dst,
                                                   int* __restrict__ deg) {
    int b = blockIdx.x, tid = threadIdx.x;
    if (b < 128) {
        int t2 = b * 256 + tid;                   // 0..32767
        const float* W = (t2 < 16384) ? W1 : W2;
        unsigned short* wt = (t2 < 16384) ? wt1 : wt2;
        int t = t2 & 16383;
        int n = t >> 7, k = t & 127;
        wt[t] = (unsigned short)bf16_rne(W[k * 128 + n]);
    } else if (b < 130) {
        // E[n][k]: n<4 -> (W al)_head n ; 4<=n<8 -> (W ar)_head n-4 ; else 0
        const float* W = (b == 128) ? W1 : W2;
        const float* al = (b == 128) ? al1 : al2;
        const float* ar = (b == 128) ? ar1 : ar2;
        unsigned short* et = (b == 128) ? et1 : et2;
        for (int o = tid * 8; o < tid * 8 + 8; o++) {   // 2048 outputs
            int n = o >> 7, k = o & 127;
            float sacc = 0.f;
            if (n < 8) {
                const float* a = (n < 4) ? al : ar;
                int hh = n & 3;
                #pragma unroll 8
                for (int c = 0; c < 32; c++)
                    sacc += W[k * 128 + hh * 32 + c] * a[hh * 32 + c];
            }
            et[n * 128 + k] = (unsigned short)bf16_rne(sacc);
        }
    } else {
        int e = (b - 130) * 256 + tid;
        if (e < N_EDGES) atomicAdd(&deg[dst[e]], 1);
    }
}

// ---------------- shared GEMM tile body (MFMA, direct-global A frags, el/er via MFMA) ----------------
__device__ __forceinline__ void gemm_tile(int base, const void* __restrict__ Xv,
                                          const unsigned short* __restrict__ wt,
                                          const unsigned short* __restrict__ et,
                                          unsigned* __restrict__ Hb,
                                          float* __restrict__ EL,
                                          float* __restrict__ ER,
                                          int src_bf16,
                                          unsigned short* wsh,   // [128*128]
                                          unsigned short* esh) { // [16*136]
    int tid = threadIdx.x;
    int w = tid >> 6, lane = tid & 63;
    int q = lane >> 4, nl = lane & 15;

    const uint4* wt4 = (const uint4*)wt;
    #pragma unroll
    for (int i = 0; i < 8; i++) {
        int idx = tid + i * 256;                // 0..2047 chunks of 8 shorts
        int rn = idx >> 4, c8 = idx & 15;
        int kc = c8 >> 2, qq = c8 & 3;
        int slot = rn * 128 + ((kc ^ ((rn >> 2) & 3)) * 4 + (qq ^ (rn & 3))) * 8;
        *(uint4*)&wsh[slot] = wt4[idx];
    }
    {
        const uint4* et4 = (const uint4*)et;
        int rn = tid >> 4, c8 = tid & 15;
        *(uint4*)&esh[rn * 136 + c8 * 8] = et4[tid];
    }

    short8 afr[2][4];
    int row0 = base + w * 32 + nl;
    if (!src_bf16) {
        const float4* X4 = (const float4*)Xv;
        #pragma unroll
        for (int rt = 0; rt < 2; rt++) {
            int rr = row0 + rt * 16; if (rr > N_NODES - 1) rr = N_NODES - 1;
            const float4* px = X4 + (size_t)rr * 32 + q * 2;
            #pragma unroll
            for (int kc = 0; kc < 4; kc++) {
                float4 u = px[kc * 8], v = px[kc * 8 + 1];
                short8 f;
                f[0] = (short)bf16_rne(u.x); f[1] = (short)bf16_rne(u.y);
                f[2] = (short)bf16_rne(u.z); f[3] = (short)bf16_rne(u.w);
                f[4] = (short)bf16_rne(v.x); f[5] = (short)bf16_rne(v.y);
                f[6] = (short)bf16_rne(v.z); f[7] = (short)bf16_rne(v.w);
                afr[rt][kc] = f;
            }
        }
    } else {
        const unsigned short* Xb = (const unsigned short*)Xv;
        #pragma unroll
        for (int rt = 0; rt < 2; rt++) {
            int rr = row0 + rt * 16; if (rr > N_NODES - 1) rr = N_NODES - 1;
            #pragma unroll
            for (int kc = 0; kc < 4; kc++)
                afr[rt][kc] = *(const short8*)(Xb + (size_t)rr * 128 + kc * 32 + q * 8);
        }
    }

    floatx4 acc[2][8];
    floatx4 acc_e[2];
    #pragma unroll
    for (int rt = 0; rt < 2; rt++) {
        acc_e[rt] = (floatx4){0.f, 0.f, 0.f, 0.f};
        #pragma unroll
        for (int ct = 0; ct < 8; ct++)
            acc[rt][ct] = (floatx4){0.f, 0.f, 0.f, 0.f};
    }

    __syncthreads();

    int sw_hi = (nl >> 2) & 3, sw_lo = nl & 3;
    #pragma unroll
    for (int ct = 0; ct < 8; ct++) {
        int rbase = (ct * 16 + nl) * 128;
        #pragma unroll
        for (int kc = 0; kc < 4; kc++) {
            short8 b = *(const short8*)&wsh[rbase + ((kc ^ sw_hi) * 4 + (q ^ sw_lo)) * 8];
            acc[0][ct] = __builtin_amdgcn_mfma_f32_16x16x32_bf16(afr[0][kc], b, acc[0][ct], 0, 0, 0);
            acc[1][ct] = __builtin_amdgcn_mfma_f32_16x16x32_bf16(afr[1][kc], b, acc[1][ct], 0, 0, 0);
        }
    }
    #pragma unroll
    for (int kc = 0; kc < 4; kc++) {
        short8 e8 = *(const short8*)&esh[nl * 136 + (kc * 4 + q) * 8];
        acc_e[0] = __builtin_amdgcn_mfma_f32_16x16x32_bf16(afr[0][kc], e8, acc_e[0], 0, 0, 0);
        acc_e[1] = __builtin_amdgcn_mfma_f32_16x16x32_bf16(afr[1][kc], e8, acc_e[1], 0, 0, 0);
    }

    #pragma unroll
    for (int rt = 0; rt < 2; rt++) {
        #pragma unroll
        for (int r = 0; r < 4; r++) {
            int row = base + w * 32 + rt * 16 + q * 4 + r;
            bool valid = row < N_NODES;
            unsigned* hrow = Hb + (size_t)row * 64;
            #pragma unroll
            for (int ct = 0; ct < 8; ct++) {
                float vlo = acc[rt][ct][r];
                float vhi = __shfl_down(vlo, 1);
                if (valid && !(nl & 1)) hrow[ct * 8 + (nl >> 1)] = bfpack(vlo, vhi);
            }
            if (valid && nl < 8) {
                float v = acc_e[rt][r];
                if (nl < 4) EL[row * 4 + nl] = v;
                else        ER[row * 4 + (nl & 3)] = v;
            }
        }
    }
}

// ---------------- K3: gemm layer-1 (blocks 0..781) + scatter (782..3906) ----------------
// Independent chains: gemm needs wt1 (K1); scatter needs cursor (K2 scan). Scatter hides under gemm.
__global__ __launch_bounds__(256) void k_gemm_scatter(const float* __restrict__ feat,
                                                      const unsigned short* __restrict__ wt1,
                                                      const unsigned short* __restrict__ et1,
                                                      unsigned* __restrict__ Hb,
                                                      float* __restrict__ EL,
                                                      float* __restrict__ ER,
                                                      const int* __restrict__ src,
                                                      const int* __restrict__ dst,
                                                      int* __restrict__ cursor,
                                                      int* __restrict__ csr_src) {
    __shared__ unsigned short wsh[128 * 128];
    __shared__ unsigned short esh[16 * 136];
    int b = blockIdx.x;
    if (b < GEMM_BLOCKS) {
        gemm_tile(b * 128, feat, wt1, et1, Hb, EL, ER, 0, wsh, esh);
    } else {
        int e = (b - GEMM_BLOCKS) * 256 + threadIdx.x;
        if (e < N_EDGES) {
            int d = dst[e];
            int p = atomicAdd(&cursor[d], 1);
            csr_src[p] = src[e];
        }
    }
}

// ---------------- K5: plain gemm (layer 2) ----------------
__global__ __launch_bounds__(256) void k_gemm(const void* __restrict__ Xv,
                                              const unsigned short* __restrict__ wt,
                                              const unsigned short* __restrict__ et,
                                              unsigned* __restrict__ Hb,
                                              float* __restrict__ EL,
                                              float* __restrict__ ER,
                                              int src_bf16) {
    __shared__ unsigned short wsh[128 * 128];
    __shared__ unsigned short esh[16 * 136];
    gemm_tile(blockIdx.x * 128, Xv, wt, et, Hb, EL, ER, src_bf16, wsh, esh);
}

// ---------------- K2: exclusive scan over deg (98 blocks, one spin-sync) ----------------
__global__ __launch_bounds__(256) void k_scan(const int* __restrict__ deg,
                                              int* __restrict__ rs,
                                              int* __restrict__ cursor,
                                              int* __restrict__ bsums,
                                              int* __restrict__ done) {
    __shared__ int sd[256];
    int tid = threadIdx.x, b = blockIdx.x;
    int base = b * 1024 + tid * 4;
    int v0 = (base + 0 < N_NODES) ? deg[base + 0] : 0;
    int v1 = (base + 1 < N_NODES) ? deg[base + 1] : 0;
    int v2 = (base + 2 < N_NODES) ? deg[base + 2] : 0;
    int v3 = (base + 3 < N_NODES) ? deg[base + 3] : 0;
    int t = v0 + v1 + v2 + v3;
    sd[tid] = t;
    __syncthreads();
    int incl = t;
    for (int off = 1; off < 256; off <<= 1) {
        int x = (tid >= off) ? sd[tid - off] : 0;
        __syncthreads();
        incl += x;
        sd[tid] = incl;
        __syncthreads();
    }
    int excl = incl - t;

    if (tid == 255) {
        atomicExch(&bsums[b], incl);
        __threadfence();
        atomicAdd(done, 1);
    }
    if (tid == 0) {
        while (atomicAdd(done, 0) < 98) { }
    }
    __syncthreads();

    int bv = (tid < b) ? atomicAdd(&bsums[tid], 0) : 0;
    __syncthreads();
    sd[tid] = bv;
    __syncthreads();
    for (int off = 128; off > 0; off >>= 1) {
        if (tid < off) sd[tid] += sd[tid + off];
        __syncthreads();
    }
    int boff = sd[0];

    int p0 = excl + boff;
    if (base + 0 < N_NODES) { rs[base + 0] = p0; cursor[base + 0] = p0; }
    if (base + 1 < N_NODES) { rs[base + 1] = p0 + v0; cursor[base + 1] = p0 + v0; }
    if (base + 2 < N_NODES) { rs[base + 2] = p0 + v0 + v1; cursor[base + 2] = p0 + v0 + v1; }
    if (base + 3 < N_NODES) { rs[base + 3] = p0 + v0 + v1 + v2; cursor[base + 3] = p0 + v0 + v1 + v2; }
    if (b == 0 && tid == 0) rs[N_NODES] = N_EDGES;
}

// ---------------- K4/K6: gather (baseline-proven: 4 nodes serial per wave, 8-edge g-split) ----------------
__global__ __launch_bounds__(256) void k_gather(const int* __restrict__ rs,
                                                const int* __restrict__ csr_src,
                                                const float* __restrict__ EL,
                                                const float* __restrict__ ER,
                                                const unsigned* __restrict__ Hb,
                                                const float* __restrict__ bias,
                                                void* __restrict__ out,
                                                int final_layer) {
    int wid = (blockIdx.x * blockDim.x + threadIdx.x) >> 6;
    int lane = threadIdx.x & 63;
    int g = lane >> 4, l16 = lane & 15;
    int h = l16 >> 2;
    int n0 = wid * 4;
    if (n0 >= N_NODES) return;
    int nend = min(n0 + 4, N_NODES);

    float bv[8];
    #pragma unroll
    for (int c = 0; c < 8; c++) bv[c] = bias[l16 * 8 + c];

    for (int n = n0; n < nend; n++) {
        int s = rs[n], e = rs[n + 1];
        float erh = ER[n * 4 + h];
        float acc[8];
        #pragma unroll
        for (int c = 0; c < 8; c++) acc[c] = 0.f;
        float sa = 0.f;

        for (int j = s; j < e; j += 8) {
            int j0 = j + g, j1 = j + 4 + g;
            uint4 p0 = make_uint4(0, 0, 0, 0), p1 = make_uint4(0, 0, 0, 0);
            float w0 = 0.f, w1 = 0.f;
            if (j0 < e) {
                int s0 = csr_src[j0];
                p0 = *(const uint4*)(Hb + (size_t)s0 * 64 + l16 * 4);
                w0 = __expf(lrelu(EL[s0 * 4 + h] + erh));
            }
            if (j1 < e) {
                int s1 = csr_src[j1];
                p1 = *(const uint4*)(Hb + (size_t)s1 * 64 + l16 * 4);
                w1 = __expf(lrelu(EL[s1 * 4 + h] + erh));
            }
            sa += w0 + w1;
            acc[0] = fmaf(bflo(p0.x), w0, acc[0]); acc[1] = fmaf(bfhi(p0.x), w0, acc[1]);
            acc[2] = fmaf(bflo(p0.y), w0, acc[2]); acc[3] = fmaf(bfhi(p0.y), w0, acc[3]);
            acc[4] = fmaf(bflo(p0.z), w0, acc[4]); acc[5] = fmaf(bfhi(p0.z), w0, acc[5]);
            acc[6] = fmaf(bflo(p0.w), w0, acc[6]); acc[7] = fmaf(bfhi(p0.w), w0, acc[7]);
            acc[0] = fmaf(bflo(p1.x), w1, acc[0]); acc[1] = fmaf(bfhi(p1.x), w1, acc[1]);
            acc[2] = fmaf(bflo(p1.y), w1, acc[2]); acc[3] = fmaf(bfhi(p1.y), w1, acc[3]);
            acc[4] = fmaf(bflo(p1.z), w1, acc[4]); acc[5] = fmaf(bfhi(p1.z), w1, acc[5]);
            acc[6] = fmaf(bflo(p1.w), w1, acc[6]); acc[7] = fmaf(bfhi(p1.w), w1, acc[7]);
        }

        #pragma unroll
        for (int c = 0; c < 8; c++) {
            acc[c] += __shfl_xor(acc[c], 16);
            acc[c] += __shfl_xor(acc[c], 32);
        }
        sa += __shfl_xor(sa, 16);
        sa += __shfl_xor(sa, 32);
        float inv = (e > s) ? 1.f / sa : 0.f;

        float r[8];
        #pragma unroll
        for (int c = 0; c < 8; c++) r[c] = acc[c] * inv + bv[c];

        if (!final_layer) {
            if (g == 0) {
                uint4 pk;
                pk.x = bfpack(fmaxf(r[0], 0.f), fmaxf(r[1], 0.f));
                pk.y = bfpack(fmaxf(r[2], 0.f), fmaxf(r[3], 0.f));
                pk.z = bfpack(fmaxf(r[4], 0.f), fmaxf(r[5], 0.f));
                pk.w = bfpack(fmaxf(r[6], 0.f), fmaxf(r[7], 0.f));
                *(uint4*)((unsigned*)out + (size_t)n * 64 + l16 * 4) = pk;
            }
        } else {
            #pragma unroll
            for (int c = 0; c < 8; c++) {
                r[c] += __shfl_xor(r[c], 4);
                r[c] += __shfl_xor(r[c], 8);
            }
            if (g == 0 && l16 < 4) {
                float* po = (float*)out + (size_t)n * 32 + l16 * 8;
                *(float4*)po = make_float4(0.25f * r[0], 0.25f * r[1], 0.25f * r[2], 0.25f * r[3]);
                *(float4*)(po + 4) = make_float4(0.25f * r[4], 0.25f * r[5], 0.25f * r[6], 0.25f * r[7]);
            }
        }
    }
}

extern "C" void kernel_launch(void* const* d_in, const int* in_sizes, int n_in,
                              void* d_out, int out_size, void* d_ws, size_t ws_size,
                              hipStream_t stream) {
    const float* feat = (const float*)d_in[0];
    const int* src = (const int*)d_in[1];
    const int* dst = (const int*)d_in[2];
    const float* W1 = (const float*)d_in[3];
    const float* al1 = (const float*)d_in[4];
    const float* ar1 = (const float*)d_in[5];
    const float* b1 = (const float*)d_in[6];
    const float* W2 = (const float*)d_in[7];
    const float* al2 = (const float*)d_in[8];
    const float* ar2 = (const float*)d_in[9];
    const float* b2 = (const float*)d_in[10];
    float* out = (float*)d_out;

    char* ws = (char*)d_ws;
    size_t off = 0;
    auto alloc = [&](size_t bytes) {
        void* p = ws + off;
        off += (bytes + 255) & ~(size_t)255;
        return p;
    };
    // deg + done first and adjacent: zeroed by one hipMemsetAsync
    int* deg = (int*)alloc((size_t)N_NODES * 4);
    int* done = (int*)alloc(256);
    size_t zero_bytes = off;                       // covers deg + done
    int* rs = (int*)alloc(((size_t)N_NODES + 1) * 4);
    int* cursor = (int*)alloc((size_t)N_NODES * 4);
    int* bsums = (int*)alloc(128 * 4);
    int* csr_src = (int*)alloc((size_t)N_EDGES * 4);
    unsigned* Hb = (unsigned*)alloc((size_t)N_NODES * 64 * 4);     // bf16 H pairs
    float* el = (float*)alloc((size_t)N_NODES * 4 * 4);
    float* er = (float*)alloc((size_t)N_NODES * 4 * 4);
    unsigned* out1b = (unsigned*)alloc((size_t)N_NODES * 64 * 4);  // bf16 relu(out1)
    unsigned short* wt1 = (unsigned short*)alloc(128 * 128 * 2);
    unsigned short* wt2 = (unsigned short*)alloc(128 * 128 * 2);
    unsigned short* et1 = (unsigned short*)alloc(16 * 128 * 2);
    unsigned short* et2 = (unsigned short*)alloc(16 * 128 * 2);

    int gat_blocks = (N_NODES + 15) / 16;

    // K0: zero deg+done (memset node, graph-capturable)
    hipMemsetAsync(ws, 0, zero_bytes, stream);
    // K1: wprep + E + histogram (hist co-scheduled with weight prep)
    k_prep_hist<<<130 + HIST_BLOCKS, 256, 0, stream>>>(W1, al1, ar1, W2, al2, ar2,
                                                       wt1, wt2, et1, et2, dst, deg);
    // K2: scan
    k_scan<<<98, 256, 0, stream>>>(deg, rs, cursor, bsums, done);
    // K3: layer-1 GEMM co-scheduled with scatter (independent chains)
    k_gemm_scatter<<<GEMM_BLOCKS + HIST_BLOCKS, 256, 0, stream>>>(feat, wt1, et1, Hb, el, er,
                                                                  src, dst, cursor, csr_src);
    // K4: gather layer 1
    k_gather<<<gat_blocks, 256, 0, stream>>>(rs, csr_src, el, er, Hb, b1, out1b, 0);
    // K5: gemm layer 2   K6: gather layer 2
    k_gemm<<<GEMM_BLOCKS, 256, 0, stream>>>(out1b, wt2, et2, Hb, el, er, 1);
    k_gather<<<gat_blocks, 256, 0, stream>>>(rs, csr_src, el, er, Hb, b2, out, 1);
}

// Round 5
// 318.881 us; speedup vs baseline: 1.1856x; 1.0170x over previous
//
#include <hip/hip_runtime.h>
#include <math.h>

#define N_NODES 100000
#define N_EDGES 800000
#define NEG_SLOPE 0.2f
#define GEMM_BLOCKS 782            // ceil(100000/128)
#define HIST_BLOCKS 3125           // 800000/256
#define SCAN_BLOCKS 98

typedef __attribute__((ext_vector_type(8))) short short8;
typedef __attribute__((ext_vector_type(4))) float floatx4;

__device__ __forceinline__ float lrelu(float x) { return x > 0.f ? x : NEG_SLOPE * x; }

__device__ __forceinline__ unsigned bf16_rne(float f) {
    unsigned u = __float_as_uint(f);
    return (u + 0x7fffu + ((u >> 16) & 1u)) >> 16;
}
__device__ __forceinline__ unsigned bfpack(float lo, float hi) {
    return bf16_rne(lo) | (bf16_rne(hi) << 16);
}
__device__ __forceinline__ float bflo(unsigned p) { return __uint_as_float(p << 16); }
__device__ __forceinline__ float bfhi(unsigned p) { return __uint_as_float(p & 0xffff0000u); }

// ---------------- K1: W^T (0..127) + E (128..129) + zero deg (130..227) + zero done (228) ----------------
__global__ __launch_bounds__(256) void k_prep0(const float* __restrict__ W1,
                                               const float* __restrict__ al1,
                                               const float* __restrict__ ar1,
                                               const float* __restrict__ W2,
                                               const float* __restrict__ al2,
                                               const float* __restrict__ ar2,
                                               unsigned short* __restrict__ wt1,
                                               unsigned short* __restrict__ wt2,
                                               unsigned short* __restrict__ et1,
                                               unsigned short* __restrict__ et2,
                                               int* __restrict__ deg,
                                               int* __restrict__ done) {
    int b = blockIdx.x, tid = threadIdx.x;
    if (b < 128) {
        int t2 = b * 256 + tid;                   // 0..32767
        const float* W = (t2 < 16384) ? W1 : W2;
        unsigned short* wt = (t2 < 16384) ? wt1 : wt2;
        int t = t2 & 16383;
        int n = t >> 7, k = t & 127;
        wt[t] = (unsigned short)bf16_rne(W[k * 128 + n]);
    } else if (b < 130) {
        // E[n][k]: n<4 -> (W al)_head n ; 4<=n<8 -> (W ar)_head n-4 ; else 0
        const float* W = (b == 128) ? W1 : W2;
        const float* al = (b == 128) ? al1 : al2;
        const float* ar = (b == 128) ? ar1 : ar2;
        unsigned short* et = (b == 128) ? et1 : et2;
        for (int o = tid * 8; o < tid * 8 + 8; o++) {   // 2048 outputs
            int n = o >> 7, k = o & 127;
            float sacc = 0.f;
            if (n < 8) {
                const float* a = (n < 4) ? al : ar;
                int hh = n & 3;
                #pragma unroll 8
                for (int c = 0; c < 32; c++)
                    sacc += W[k * 128 + hh * 32 + c] * a[hh * 32 + c];
            }
            et[n * 128 + k] = (unsigned short)bf16_rne(sacc);
        }
    } else if (b < 228) {
        int i = (b - 130) * 1024 + tid * 4;
        if (i + 3 < N_NODES) *(int4*)&deg[i] = make_int4(0, 0, 0, 0);
        else { for (int j = i; j < N_NODES; j++) if (j >= 0) deg[j] = 0; }
    } else {
        if (tid < 64) done[tid] = 0;
    }
}

// ---------------- shared GEMM tile body (MFMA, direct-global A frags, el/er via MFMA) ----------------
__device__ __forceinline__ void gemm_tile(int base, const void* __restrict__ Xv,
                                          const unsigned short* __restrict__ wt,
                                          const unsigned short* __restrict__ et,
                                          unsigned* __restrict__ Hb,
                                          float* __restrict__ EL,
                                          float* __restrict__ ER,
                                          int src_bf16,
                                          unsigned short* wsh,   // [128*128]
                                          unsigned short* esh) { // [16*136]
    int tid = threadIdx.x;
    int w = tid >> 6, lane = tid & 63;
    int q = lane >> 4, nl = lane & 15;

    const uint4* wt4 = (const uint4*)wt;
    #pragma unroll
    for (int i = 0; i < 8; i++) {
        int idx = tid + i * 256;                // 0..2047 chunks of 8 shorts
        int rn = idx >> 4, c8 = idx & 15;
        int kc = c8 >> 2, qq = c8 & 3;
        int slot = rn * 128 + ((kc ^ ((rn >> 2) & 3)) * 4 + (qq ^ (rn & 3))) * 8;
        *(uint4*)&wsh[slot] = wt4[idx];
    }
    {
        const uint4* et4 = (const uint4*)et;
        int rn = tid >> 4, c8 = tid & 15;
        *(uint4*)&esh[rn * 136 + c8 * 8] = et4[tid];
    }

    short8 afr[2][4];
    int row0 = base + w * 32 + nl;
    if (!src_bf16) {
        const float4* X4 = (const float4*)Xv;
        #pragma unroll
        for (int rt = 0; rt < 2; rt++) {
            int rr = row0 + rt * 16; if (rr > N_NODES - 1) rr = N_NODES - 1;
            const float4* px = X4 + (size_t)rr * 32 + q * 2;
            #pragma unroll
            for (int kc = 0; kc < 4; kc++) {
                float4 u = px[kc * 8], v = px[kc * 8 + 1];
                short8 f;
                f[0] = (short)bf16_rne(u.x); f[1] = (short)bf16_rne(u.y);
                f[2] = (short)bf16_rne(u.z); f[3] = (short)bf16_rne(u.w);
                f[4] = (short)bf16_rne(v.x); f[5] = (short)bf16_rne(v.y);
                f[6] = (short)bf16_rne(v.z); f[7] = (short)bf16_rne(v.w);
                afr[rt][kc] = f;
            }
        }
    } else {
        const unsigned short* Xb = (const unsigned short*)Xv;
        #pragma unroll
        for (int rt = 0; rt < 2; rt++) {
            int rr = row0 + rt * 16; if (rr > N_NODES - 1) rr = N_NODES - 1;
            #pragma unroll
            for (int kc = 0; kc < 4; kc++)
                afr[rt][kc] = *(const short8*)(Xb + (size_t)rr * 128 + kc * 32 + q * 8);
        }
    }

    floatx4 acc[2][8];
    floatx4 acc_e[2];
    #pragma unroll
    for (int rt = 0; rt < 2; rt++) {
        acc_e[rt] = (floatx4){0.f, 0.f, 0.f, 0.f};
        #pragma unroll
        for (int ct = 0; ct < 8; ct++)
            acc[rt][ct] = (floatx4){0.f, 0.f, 0.f, 0.f};
    }

    __syncthreads();

    int sw_hi = (nl >> 2) & 3, sw_lo = nl & 3;
    #pragma unroll
    for (int ct = 0; ct < 8; ct++) {
        int rbase = (ct * 16 + nl) * 128;
        #pragma unroll
        for (int kc = 0; kc < 4; kc++) {
            short8 b = *(const short8*)&wsh[rbase + ((kc ^ sw_hi) * 4 + (q ^ sw_lo)) * 8];
            acc[0][ct] = __builtin_amdgcn_mfma_f32_16x16x32_bf16(afr[0][kc], b, acc[0][ct], 0, 0, 0);
            acc[1][ct] = __builtin_amdgcn_mfma_f32_16x16x32_bf16(afr[1][kc], b, acc[1][ct], 0, 0, 0);
        }
    }
    #pragma unroll
    for (int kc = 0; kc < 4; kc++) {
        short8 e8 = *(const short8*)&esh[nl * 136 + (kc * 4 + q) * 8];
        acc_e[0] = __builtin_amdgcn_mfma_f32_16x16x32_bf16(afr[0][kc], e8, acc_e[0], 0, 0, 0);
        acc_e[1] = __builtin_amdgcn_mfma_f32_16x16x32_bf16(afr[1][kc], e8, acc_e[1], 0, 0, 0);
    }

    #pragma unroll
    for (int rt = 0; rt < 2; rt++) {
        #pragma unroll
        for (int r = 0; r < 4; r++) {
            int row = base + w * 32 + rt * 16 + q * 4 + r;
            bool valid = row < N_NODES;
            unsigned* hrow = Hb + (size_t)row * 64;
            #pragma unroll
            for (int ct = 0; ct < 8; ct++) {
                float vlo = acc[rt][ct][r];
                float vhi = __shfl_down(vlo, 1);
                if (valid && !(nl & 1)) hrow[ct * 8 + (nl >> 1)] = bfpack(vlo, vhi);
            }
            if (valid && nl < 8) {
                float v = acc_e[rt][r];
                if (nl < 4) EL[row * 4 + nl] = v;
                else        ER[row * 4 + (nl & 3)] = v;
            }
        }
    }
}

// ---------------- K2: gemm layer-1 (blocks 0..781) + histogram (782..3906) ----------------
// Independent chains co-scheduled: MFMA waves (gemm) + fire-and-forget atomic waves (hist).
__global__ __launch_bounds__(256) void k_gemm_hist(const float* __restrict__ feat,
                                                   const unsigned short* __restrict__ wt1,
                                                   const unsigned short* __restrict__ et1,
                                                   unsigned* __restrict__ Hb,
                                                   float* __restrict__ EL,
                                                   float* __restrict__ ER,
                                                   const int* __restrict__ dst,
                                                   int* __restrict__ deg) {
    __shared__ unsigned short wsh[128 * 128];
    __shared__ unsigned short esh[16 * 136];
    int b = blockIdx.x;
    if (b < GEMM_BLOCKS) {
        gemm_tile(b * 128, feat, wt1, et1, Hb, EL, ER, 0, wsh, esh);
    } else {
        int e = (b - GEMM_BLOCKS) * 256 + threadIdx.x;
        if (e < N_EDGES) atomicAdd(&deg[dst[e]], 1);
    }
}

// ---------------- K5: plain gemm (layer 2) ----------------
__global__ __launch_bounds__(256) void k_gemm(const void* __restrict__ Xv,
                                              const unsigned short* __restrict__ wt,
                                              const unsigned short* __restrict__ et,
                                              unsigned* __restrict__ Hb,
                                              float* __restrict__ EL,
                                              float* __restrict__ ER,
                                              int src_bf16) {
    __shared__ unsigned short wsh[128 * 128];
    __shared__ unsigned short esh[16 * 136];
    gemm_tile(blockIdx.x * 128, Xv, wt, et, Hb, EL, ER, src_bf16, wsh, esh);
}

// ---------------- K3: fused scan + scatter (98 co-resident blocks, two spin-syncs) ----------------
// Phase 1: exclusive scan over deg (identical to proven k_scan; cursor via atomicExch for
// cross-XCD coherence). Phase 2 (after grid sync #2): grid-stride scatter, 4-wide batched.
__global__ __launch_bounds__(256) void k_scan_scatter(const int* __restrict__ deg,
                                                      int* __restrict__ rs,
                                                      int* __restrict__ cursor,
                                                      int* __restrict__ bsums,
                                                      int* __restrict__ done,
                                                      const int* __restrict__ src,
                                                      const int* __restrict__ dst,
                                                      int* __restrict__ csr_src) {
    __shared__ int sd[256];
    int tid = threadIdx.x, b = blockIdx.x;
    int base = b * 1024 + tid * 4;
    int v0 = (base + 0 < N_NODES) ? deg[base + 0] : 0;
    int v1 = (base + 1 < N_NODES) ? deg[base + 1] : 0;
    int v2 = (base + 2 < N_NODES) ? deg[base + 2] : 0;
    int v3 = (base + 3 < N_NODES) ? deg[base + 3] : 0;
    int t = v0 + v1 + v2 + v3;
    sd[tid] = t;
    __syncthreads();
    int incl = t;
    for (int off = 1; off < 256; off <<= 1) {
        int x = (tid >= off) ? sd[tid - off] : 0;
        __syncthreads();
        incl += x;
        sd[tid] = incl;
        __syncthreads();
    }
    int excl = incl - t;

    if (tid == 255) {
        atomicExch(&bsums[b], incl);
        __threadfence();
        atomicAdd(&done[0], 1);
    }
    if (tid == 0) {
        while (atomicAdd(&done[0], 0) < SCAN_BLOCKS) { }
    }
    __syncthreads();

    int bv = (tid < b) ? atomicAdd(&bsums[tid], 0) : 0;
    __syncthreads();
    sd[tid] = bv;
    __syncthreads();
    for (int off = 128; off > 0; off >>= 1) {
        if (tid < off) sd[tid] += sd[tid + off];
        __syncthreads();
    }
    int boff = sd[0];

    int p0 = excl + boff;
    // rs: plain stores (read only by later kernels). cursor: atomicExch (read via atomics
    // by OTHER blocks/XCDs within this kernel -> must live at the coherent point).
    if (base + 0 < N_NODES) { rs[base + 0] = p0;                atomicExch(&cursor[base + 0], p0); }
    if (base + 1 < N_NODES) { rs[base + 1] = p0 + v0;           atomicExch(&cursor[base + 1], p0 + v0); }
    if (base + 2 < N_NODES) { rs[base + 2] = p0 + v0 + v1;      atomicExch(&cursor[base + 2], p0 + v0 + v1); }
    if (base + 3 < N_NODES) { rs[base + 3] = p0 + v0 + v1 + v2; atomicExch(&cursor[base + 3], p0 + v0 + v1 + v2); }
    if (b == 0 && tid == 0) rs[N_NODES] = N_EDGES;

    // ---- grid sync #2: all cursor slots initialized before any scatter atomic ----
    __threadfence();
    __syncthreads();
    if (tid == 0) {
        atomicAdd(&done[1], 1);
        while (atomicAdd(&done[1], 0) < SCAN_BLOCKS) { }
    }
    __syncthreads();

    // ---- phase 2: scatter, grid-stride, 4 independent atomic chains in flight ----
    const int stride = SCAN_BLOCKS * 256;
    int e = b * 256 + tid;
    while (e + 3 * stride < N_EDGES) {
        int d0 = dst[e];             int s0 = src[e];
        int d1 = dst[e + stride];    int s1 = src[e + stride];
        int d2 = dst[e + 2*stride];  int s2 = src[e + 2*stride];
        int d3 = dst[e + 3*stride];  int s3 = src[e + 3*stride];
        int q0 = atomicAdd(&cursor[d0], 1);
        int q1 = atomicAdd(&cursor[d1], 1);
        int q2 = atomicAdd(&cursor[d2], 1);
        int q3 = atomicAdd(&cursor[d3], 1);
        csr_src[q0] = s0;
        csr_src[q1] = s1;
        csr_src[q2] = s2;
        csr_src[q3] = s3;
        e += 4 * stride;
    }
    for (; e < N_EDGES; e += stride) {
        int d = dst[e];
        int p = atomicAdd(&cursor[d], 1);
        csr_src[p] = src[e];
    }
}

// ---------------- K4/K6: gather (baseline-proven: 4 nodes serial per wave, 8-edge g-split) ----------------
__global__ __launch_bounds__(256) void k_gather(const int* __restrict__ rs,
                                                const int* __restrict__ csr_src,
                                                const float* __restrict__ EL,
                                                const float* __restrict__ ER,
                                                const unsigned* __restrict__ Hb,
                                                const float* __restrict__ bias,
                                                void* __restrict__ out,
                                                int final_layer) {
    int wid = (blockIdx.x * blockDim.x + threadIdx.x) >> 6;
    int lane = threadIdx.x & 63;
    int g = lane >> 4, l16 = lane & 15;
    int h = l16 >> 2;
    int n0 = wid * 4;
    if (n0 >= N_NODES) return;
    int nend = min(n0 + 4, N_NODES);

    float bv[8];
    #pragma unroll
    for (int c = 0; c < 8; c++) bv[c] = bias[l16 * 8 + c];

    for (int n = n0; n < nend; n++) {
        int s = rs[n], e = rs[n + 1];
        float erh = ER[n * 4 + h];
        float acc[8];
        #pragma unroll
        for (int c = 0; c < 8; c++) acc[c] = 0.f;
        float sa = 0.f;

        for (int j = s; j < e; j += 8) {
            int j0 = j + g, j1 = j + 4 + g;
            uint4 p0 = make_uint4(0, 0, 0, 0), p1 = make_uint4(0, 0, 0, 0);
            float w0 = 0.f, w1 = 0.f;
            if (j0 < e) {
                int s0 = csr_src[j0];
                p0 = *(const uint4*)(Hb + (size_t)s0 * 64 + l16 * 4);
                w0 = __expf(lrelu(EL[s0 * 4 + h] + erh));
            }
            if (j1 < e) {
                int s1 = csr_src[j1];
                p1 = *(const uint4*)(Hb + (size_t)s1 * 64 + l16 * 4);
                w1 = __expf(lrelu(EL[s1 * 4 + h] + erh));
            }
            sa += w0 + w1;
            acc[0] = fmaf(bflo(p0.x), w0, acc[0]); acc[1] = fmaf(bfhi(p0.x), w0, acc[1]);
            acc[2] = fmaf(bflo(p0.y), w0, acc[2]); acc[3] = fmaf(bfhi(p0.y), w0, acc[3]);
            acc[4] = fmaf(bflo(p0.z), w0, acc[4]); acc[5] = fmaf(bfhi(p0.z), w0, acc[5]);
            acc[6] = fmaf(bflo(p0.w), w0, acc[6]); acc[7] = fmaf(bfhi(p0.w), w0, acc[7]);
            acc[0] = fmaf(bflo(p1.x), w1, acc[0]); acc[1] = fmaf(bfhi(p1.x), w1, acc[1]);
            acc[2] = fmaf(bflo(p1.y), w1, acc[2]); acc[3] = fmaf(bfhi(p1.y), w1, acc[3]);
            acc[4] = fmaf(bflo(p1.z), w1, acc[4]); acc[5] = fmaf(bfhi(p1.z), w1, acc[5]);
            acc[6] = fmaf(bflo(p1.w), w1, acc[6]); acc[7] = fmaf(bfhi(p1.w), w1, acc[7]);
        }

        #pragma unroll
        for (int c = 0; c < 8; c++) {
            acc[c] += __shfl_xor(acc[c], 16);
            acc[c] += __shfl_xor(acc[c], 32);
        }
        sa += __shfl_xor(sa, 16);
        sa += __shfl_xor(sa, 32);
        float inv = (e > s) ? 1.f / sa : 0.f;

        float r[8];
        #pragma unroll
        for (int c = 0; c < 8; c++) r[c] = acc[c] * inv + bv[c];

        if (!final_layer) {
            if (g == 0) {
                uint4 pk;
                pk.x = bfpack(fmaxf(r[0], 0.f), fmaxf(r[1], 0.f));
                pk.y = bfpack(fmaxf(r[2], 0.f), fmaxf(r[3], 0.f));
                pk.z = bfpack(fmaxf(r[4], 0.f), fmaxf(r[5], 0.f));
                pk.w = bfpack(fmaxf(r[6], 0.f), fmaxf(r[7], 0.f));
                *(uint4*)((unsigned*)out + (size_t)n * 64 + l16 * 4) = pk;
            }
        } else {
            #pragma unroll
            for (int c = 0; c < 8; c++) {
                r[c] += __shfl_xor(r[c], 4);
                r[c] += __shfl_xor(r[c], 8);
            }
            if (g == 0 && l16 < 4) {
                float* po = (float*)out + (size_t)n * 32 + l16 * 8;
                *(float4*)po = make_float4(0.25f * r[0], 0.25f * r[1], 0.25f * r[2], 0.25f * r[3]);
                *(float4*)(po + 4) = make_float4(0.25f * r[4], 0.25f * r[5], 0.25f * r[6], 0.25f * r[7]);
            }
        }
    }
}

extern "C" void kernel_launch(void* const* d_in, const int* in_sizes, int n_in,
                              void* d_out, int out_size, void* d_ws, size_t ws_size,
                              hipStream_t stream) {
    const float* feat = (const float*)d_in[0];
    const int* src = (const int*)d_in[1];
    const int* dst = (const int*)d_in[2];
    const float* W1 = (const float*)d_in[3];
    const float* al1 = (const float*)d_in[4];
    const float* ar1 = (const float*)d_in[5];
    const float* b1 = (const float*)d_in[6];
    const float* W2 = (const float*)d_in[7];
    const float* al2 = (const float*)d_in[8];
    const float* ar2 = (const float*)d_in[9];
    const float* b2 = (const float*)d_in[10];
    float* out = (float*)d_out;

    char* ws = (char*)d_ws;
    size_t off = 0;
    auto alloc = [&](size_t bytes) {
        void* p = ws + off;
        off += (bytes + 255) & ~(size_t)255;
        return p;
    };
    int* deg = (int*)alloc((size_t)N_NODES * 4);
    int* done = (int*)alloc(256);
    int* rs = (int*)alloc(((size_t)N_NODES + 1) * 4);
    int* cursor = (int*)alloc((size_t)N_NODES * 4);
    int* bsums = (int*)alloc(128 * 4);
    int* csr_src = (int*)alloc((size_t)N_EDGES * 4);
    unsigned* Hb = (unsigned*)alloc((size_t)N_NODES * 64 * 4);     // bf16 H pairs
    float* el = (float*)alloc((size_t)N_NODES * 4 * 4);
    float* er = (float*)alloc((size_t)N_NODES * 4 * 4);
    unsigned* out1b = (unsigned*)alloc((size_t)N_NODES * 64 * 4);  // bf16 relu(out1)
    unsigned short* wt1 = (unsigned short*)alloc(128 * 128 * 2);
    unsigned short* wt2 = (unsigned short*)alloc(128 * 128 * 2);
    unsigned short* et1 = (unsigned short*)alloc(16 * 128 * 2);
    unsigned short* et2 = (unsigned short*)alloc(16 * 128 * 2);

    int gat_blocks = (N_NODES + 15) / 16;

    // K1: wprep + E + zero deg/done
    k_prep0<<<229, 256, 0, stream>>>(W1, al1, ar1, W2, al2, ar2,
                                     wt1, wt2, et1, et2, deg, done);
    // K2: layer-1 GEMM co-scheduled with fire-and-forget histogram
    k_gemm_hist<<<GEMM_BLOCKS + HIST_BLOCKS, 256, 0, stream>>>(feat, wt1, et1, Hb, el, er,
                                                               dst, deg);
    // K3: fused scan + scatter (saves one dispatch + the standalone scatter pass)
    k_scan_scatter<<<SCAN_BLOCKS, 256, 0, stream>>>(deg, rs, cursor, bsums, done,
                                                    src, dst, csr_src);
    // K4: gather layer 1
    k_gather<<<gat_blocks, 256, 0, stream>>>(rs, csr_src, el, er, Hb, b1, out1b, 0);
    // K5: gemm layer 2   K6: gather layer 2
    k_gemm<<<GEMM_BLOCKS, 256, 0, stream>>>(out1b, wt2, et2, Hb, el, er, 1);
    k_gather<<<gat_blocks, 256, 0, stream>>>(rs, csr_src, el, er, Hb, b2, out, 1);
}

// Round 6
// 310.726 us; speedup vs baseline: 1.2167x; 1.0262x over previous
//
#include <hip/hip_runtime.h>
#include <math.h>

#define N_NODES 100000
#define N_EDGES 800000
#define NEG_SLOPE 0.2f
#define GEMM_BLOCKS 782            // ceil(100000/128)
#define HIST4_BLOCKS 782           // ceil(800000/1024), 4 edges/thread
#define SCAN_BLOCKS 98

typedef __attribute__((ext_vector_type(8))) short short8;
typedef __attribute__((ext_vector_type(4))) float floatx4;

__device__ __forceinline__ float lrelu(float x) { return x > 0.f ? x : NEG_SLOPE * x; }

__device__ __forceinline__ unsigned bf16_rne(float f) {
    unsigned u = __float_as_uint(f);
    return (u + 0x7fffu + ((u >> 16) & 1u)) >> 16;
}
__device__ __forceinline__ unsigned bfpack(float lo, float hi) {
    return bf16_rne(lo) | (bf16_rne(hi) << 16);
}
__device__ __forceinline__ float bflo(unsigned p) { return __uint_as_float(p << 16); }
__device__ __forceinline__ float bfhi(unsigned p) { return __uint_as_float(p & 0xffff0000u); }

// ---------------- K1: W^T (0..127) + E (128..129) + zero deg (130..227) + zero done (228) ----------------
__global__ __launch_bounds__(256) void k_prep0(const float* __restrict__ W1,
                                               const float* __restrict__ al1,
                                               const float* __restrict__ ar1,
                                               const float* __restrict__ W2,
                                               const float* __restrict__ al2,
                                               const float* __restrict__ ar2,
                                               unsigned short* __restrict__ wt1,
                                               unsigned short* __restrict__ wt2,
                                               unsigned short* __restrict__ et1,
                                               unsigned short* __restrict__ et2,
                                               int* __restrict__ deg,
                                               int* __restrict__ done) {
    int b = blockIdx.x, tid = threadIdx.x;
    if (b < 128) {
        int t2 = b * 256 + tid;                   // 0..32767
        const float* W = (t2 < 16384) ? W1 : W2;
        unsigned short* wt = (t2 < 16384) ? wt1 : wt2;
        int t = t2 & 16383;
        int n = t >> 7, k = t & 127;
        wt[t] = (unsigned short)bf16_rne(W[k * 128 + n]);
    } else if (b < 130) {
        // E[n][k]: n<4 -> (W al)_head n ; 4<=n<8 -> (W ar)_head n-4 ; else 0
        const float* W = (b == 128) ? W1 : W2;
        const float* al = (b == 128) ? al1 : al2;
        const float* ar = (b == 128) ? ar1 : ar2;
        unsigned short* et = (b == 128) ? et1 : et2;
        for (int o = tid * 8; o < tid * 8 + 8; o++) {   // 2048 outputs
            int n = o >> 7, k = o & 127;
            float sacc = 0.f;
            if (n < 8) {
                const float* a = (n < 4) ? al : ar;
                int hh = n & 3;
                #pragma unroll 8
                for (int c = 0; c < 32; c++)
                    sacc += W[k * 128 + hh * 32 + c] * a[hh * 32 + c];
            }
            et[n * 128 + k] = (unsigned short)bf16_rne(sacc);
        }
    } else if (b < 228) {
        int i = (b - 130) * 1024 + tid * 4;
        if (i + 3 < N_NODES) *(int4*)&deg[i] = make_int4(0, 0, 0, 0);
        else { for (int j = i; j < N_NODES; j++) if (j >= 0) deg[j] = 0; }
    } else {
        if (tid < 64) done[tid] = 0;
    }
}

// ---------------- shared GEMM tile body (MFMA, direct-global A frags, el/er via MFMA) ----------------
__device__ __forceinline__ void gemm_tile(int base, const void* __restrict__ Xv,
                                          const unsigned short* __restrict__ wt,
                                          const unsigned short* __restrict__ et,
                                          unsigned* __restrict__ Hb,
                                          float* __restrict__ EL,
                                          float* __restrict__ ER,
                                          int src_bf16,
                                          unsigned short* wsh,   // [128*128]
                                          unsigned short* esh) { // [16*136]
    int tid = threadIdx.x;
    int w = tid >> 6, lane = tid & 63;
    int q = lane >> 4, nl = lane & 15;

    const uint4* wt4 = (const uint4*)wt;
    #pragma unroll
    for (int i = 0; i < 8; i++) {
        int idx = tid + i * 256;                // 0..2047 chunks of 8 shorts
        int rn = idx >> 4, c8 = idx & 15;
        int kc = c8 >> 2, qq = c8 & 3;
        int slot = rn * 128 + ((kc ^ ((rn >> 2) & 3)) * 4 + (qq ^ (rn & 3))) * 8;
        *(uint4*)&wsh[slot] = wt4[idx];
    }
    {
        const uint4* et4 = (const uint4*)et;
        int rn = tid >> 4, c8 = tid & 15;
        *(uint4*)&esh[rn * 136 + c8 * 8] = et4[tid];
    }

    short8 afr[2][4];
    int row0 = base + w * 32 + nl;
    if (!src_bf16) {
        const float4* X4 = (const float4*)Xv;
        #pragma unroll
        for (int rt = 0; rt < 2; rt++) {
            int rr = row0 + rt * 16; if (rr > N_NODES - 1) rr = N_NODES - 1;
            const float4* px = X4 + (size_t)rr * 32 + q * 2;
            #pragma unroll
            for (int kc = 0; kc < 4; kc++) {
                float4 u = px[kc * 8], v = px[kc * 8 + 1];
                short8 f;
                f[0] = (short)bf16_rne(u.x); f[1] = (short)bf16_rne(u.y);
                f[2] = (short)bf16_rne(u.z); f[3] = (short)bf16_rne(u.w);
                f[4] = (short)bf16_rne(v.x); f[5] = (short)bf16_rne(v.y);
                f[6] = (short)bf16_rne(v.z); f[7] = (short)bf16_rne(v.w);
                afr[rt][kc] = f;
            }
        }
    } else {
        const unsigned short* Xb = (const unsigned short*)Xv;
        #pragma unroll
        for (int rt = 0; rt < 2; rt++) {
            int rr = row0 + rt * 16; if (rr > N_NODES - 1) rr = N_NODES - 1;
            #pragma unroll
            for (int kc = 0; kc < 4; kc++)
                afr[rt][kc] = *(const short8*)(Xb + (size_t)rr * 128 + kc * 32 + q * 8);
        }
    }

    floatx4 acc[2][8];
    floatx4 acc_e[2];
    #pragma unroll
    for (int rt = 0; rt < 2; rt++) {
        acc_e[rt] = (floatx4){0.f, 0.f, 0.f, 0.f};
        #pragma unroll
        for (int ct = 0; ct < 8; ct++)
            acc[rt][ct] = (floatx4){0.f, 0.f, 0.f, 0.f};
    }

    __syncthreads();

    int sw_hi = (nl >> 2) & 3, sw_lo = nl & 3;
    #pragma unroll
    for (int ct = 0; ct < 8; ct++) {
        int rbase = (ct * 16 + nl) * 128;
        #pragma unroll
        for (int kc = 0; kc < 4; kc++) {
            short8 b = *(const short8*)&wsh[rbase + ((kc ^ sw_hi) * 4 + (q ^ sw_lo)) * 8];
            acc[0][ct] = __builtin_amdgcn_mfma_f32_16x16x32_bf16(afr[0][kc], b, acc[0][ct], 0, 0, 0);
            acc[1][ct] = __builtin_amdgcn_mfma_f32_16x16x32_bf16(afr[1][kc], b, acc[1][ct], 0, 0, 0);
        }
    }
    #pragma unroll
    for (int kc = 0; kc < 4; kc++) {
        short8 e8 = *(const short8*)&esh[nl * 136 + (kc * 4 + q) * 8];
        acc_e[0] = __builtin_amdgcn_mfma_f32_16x16x32_bf16(afr[0][kc], e8, acc_e[0], 0, 0, 0);
        acc_e[1] = __builtin_amdgcn_mfma_f32_16x16x32_bf16(afr[1][kc], e8, acc_e[1], 0, 0, 0);
    }

    #pragma unroll
    for (int rt = 0; rt < 2; rt++) {
        #pragma unroll
        for (int r = 0; r < 4; r++) {
            int row = base + w * 32 + rt * 16 + q * 4 + r;
            bool valid = row < N_NODES;
            unsigned* hrow = Hb + (size_t)row * 64;
            #pragma unroll
            for (int ct = 0; ct < 8; ct++) {
                float vlo = acc[rt][ct][r];
                float vhi = __shfl_down(vlo, 1);
                if (valid && !(nl & 1)) hrow[ct * 8 + (nl >> 1)] = bfpack(vlo, vhi);
            }
            if (valid && nl < 8) {
                float v = acc_e[rt][r];
                if (nl < 4) EL[row * 4 + nl] = v;
                else        ER[row * 4 + (nl & 3)] = v;
            }
        }
    }
}

// ---------------- K2: gemm layer-1 (blocks 0..781) + rank-histogram (782..1563) ----------------
// Hist stores the atomicAdd return (slot rank) to a COALESCED edge-indexed array. 4 edges/thread
// so 4 atomic round-trips are in flight per thread (hides return latency under the LDS occupancy cap).
__global__ __launch_bounds__(256) void k_gemm_hist(const float* __restrict__ feat,
                                                   const unsigned short* __restrict__ wt1,
                                                   const unsigned short* __restrict__ et1,
                                                   unsigned* __restrict__ Hb,
                                                   float* __restrict__ EL,
                                                   float* __restrict__ ER,
                                                   const int* __restrict__ dst,
                                                   int* __restrict__ deg,
                                                   unsigned short* __restrict__ rank) {
    __shared__ unsigned short wsh[128 * 128];
    __shared__ unsigned short esh[16 * 136];
    int b = blockIdx.x;
    if (b < GEMM_BLOCKS) {
        gemm_tile(b * 128, feat, wt1, et1, Hb, EL, ER, 0, wsh, esh);
    } else {
        int ebase = (b - GEMM_BLOCKS) * 1024 + threadIdx.x;
        int d[4], c[4];
        #pragma unroll
        for (int k = 0; k < 4; k++) {
            int e = ebase + k * 256;
            d[k] = (e < N_EDGES) ? dst[e] : 0;
        }
        #pragma unroll
        for (int k = 0; k < 4; k++) {
            int e = ebase + k * 256;
            c[k] = (e < N_EDGES) ? atomicAdd(&deg[d[k]], 1) : 0;
        }
        #pragma unroll
        for (int k = 0; k < 4; k++) {
            int e = ebase + k * 256;
            if (e < N_EDGES) rank[e] = (unsigned short)c[k];
        }
    }
}

// ---------------- K5: plain gemm (layer 2) ----------------
__global__ __launch_bounds__(256) void k_gemm(const void* __restrict__ Xv,
                                              const unsigned short* __restrict__ wt,
                                              const unsigned short* __restrict__ et,
                                              unsigned* __restrict__ Hb,
                                              float* __restrict__ EL,
                                              float* __restrict__ ER,
                                              int src_bf16) {
    __shared__ unsigned short wsh[128 * 128];
    __shared__ unsigned short esh[16 * 136];
    gemm_tile(blockIdx.x * 128, Xv, wt, et, Hb, EL, ER, src_bf16, wsh, esh);
}

// ---------------- K3: scan + atomic-free scatter (98 co-resident blocks, two spin-syncs) ----------------
// Phase 1: exclusive scan over deg; rs written via atomicExch (coherence point) so phase-2's
// cross-XCD plain reads are safe. Phase 2: csr_src[rs[dst]+rank] = src -- ZERO atomics, pure BW.
__global__ __launch_bounds__(256) void k_scan_scatter(const int* __restrict__ deg,
                                                      int* __restrict__ rs,
                                                      int* __restrict__ bsums,
                                                      int* __restrict__ done,
                                                      const int* __restrict__ src,
                                                      const int* __restrict__ dst,
                                                      const unsigned short* __restrict__ rank,
                                                      int* __restrict__ csr_src) {
    __shared__ int sd[256];
    int tid = threadIdx.x, b = blockIdx.x;
    int base = b * 1024 + tid * 4;
    int v0 = (base + 0 < N_NODES) ? deg[base + 0] : 0;
    int v1 = (base + 1 < N_NODES) ? deg[base + 1] : 0;
    int v2 = (base + 2 < N_NODES) ? deg[base + 2] : 0;
    int v3 = (base + 3 < N_NODES) ? deg[base + 3] : 0;
    int t = v0 + v1 + v2 + v3;
    sd[tid] = t;
    __syncthreads();
    int incl = t;
    for (int off = 1; off < 256; off <<= 1) {
        int x = (tid >= off) ? sd[tid - off] : 0;
        __syncthreads();
        incl += x;
        sd[tid] = incl;
        __syncthreads();
    }
    int excl = incl - t;

    if (tid == 255) {
        atomicExch(&bsums[b], incl);
        __threadfence();
        atomicAdd(&done[0], 1);
    }
    if (tid == 0) {
        while (atomicAdd(&done[0], 0) < SCAN_BLOCKS) { }
    }
    __syncthreads();

    int bv = (tid < b) ? atomicAdd(&bsums[tid], 0) : 0;
    __syncthreads();
    sd[tid] = bv;
    __syncthreads();
    for (int off = 128; off > 0; off >>= 1) {
        if (tid < off) sd[tid] += sd[tid + off];
        __syncthreads();
    }
    int boff = sd[0];

    int p0 = excl + boff;
    // rs written with atomicExch: lands at the coherence point so other blocks/XCDs can
    // plain-read it in phase 2 (their L2s hold no stale copy within this kernel).
    if (base + 0 < N_NODES) atomicExch(&rs[base + 0], p0);
    if (base + 1 < N_NODES) atomicExch(&rs[base + 1], p0 + v0);
    if (base + 2 < N_NODES) atomicExch(&rs[base + 2], p0 + v0 + v1);
    if (base + 3 < N_NODES) atomicExch(&rs[base + 3], p0 + v0 + v1 + v2);
    if (b == 0 && tid == 0) atomicExch(&rs[N_NODES], N_EDGES);

    // ---- grid sync #2: all rs slots written before any phase-2 read ----
    __threadfence();
    __syncthreads();
    if (tid == 0) {
        atomicAdd(&done[1], 1);
        while (atomicAdd(&done[1], 0) < SCAN_BLOCKS) { }
    }
    __syncthreads();

    // ---- phase 2: atomic-free scatter, grid-stride, 4-wide ----
    const int stride = SCAN_BLOCKS * 256;
    int e = b * 256 + tid;
    while (e + 3 * stride < N_EDGES) {
        int e1 = e + stride, e2 = e + 2 * stride, e3 = e + 3 * stride;
        int d0 = dst[e],  d1 = dst[e1], d2 = dst[e2], d3 = dst[e3];
        int s0 = src[e],  s1 = src[e1], s2 = src[e2], s3 = src[e3];
        int r0 = rank[e], r1 = rank[e1], r2 = rank[e2], r3 = rank[e3];
        int q0 = rs[d0], q1 = rs[d1], q2 = rs[d2], q3 = rs[d3];
        csr_src[q0 + r0] = s0;
        csr_src[q1 + r1] = s1;
        csr_src[q2 + r2] = s2;
        csr_src[q3 + r3] = s3;
        e += 4 * stride;
    }
    for (; e < N_EDGES; e += stride) {
        csr_src[rs[dst[e]] + rank[e]] = src[e];
    }
}

// ---------------- K4/K6: gather (baseline-proven: 4 nodes serial per wave, 8-edge g-split) ----------------
__global__ __launch_bounds__(256) void k_gather(const int* __restrict__ rs,
                                                const int* __restrict__ csr_src,
                                                const float* __restrict__ EL,
                                                const float* __restrict__ ER,
                                                const unsigned* __restrict__ Hb,
                                                const float* __restrict__ bias,
                                                void* __restrict__ out,
                                                int final_layer) {
    int wid = (blockIdx.x * blockDim.x + threadIdx.x) >> 6;
    int lane = threadIdx.x & 63;
    int g = lane >> 4, l16 = lane & 15;
    int h = l16 >> 2;
    int n0 = wid * 4;
    if (n0 >= N_NODES) return;
    int nend = min(n0 + 4, N_NODES);

    float bv[8];
    #pragma unroll
    for (int c = 0; c < 8; c++) bv[c] = bias[l16 * 8 + c];

    for (int n = n0; n < nend; n++) {
        int s = rs[n], e = rs[n + 1];
        float erh = ER[n * 4 + h];
        float acc[8];
        #pragma unroll
        for (int c = 0; c < 8; c++) acc[c] = 0.f;
        float sa = 0.f;

        for (int j = s; j < e; j += 8) {
            int j0 = j + g, j1 = j + 4 + g;
            uint4 p0 = make_uint4(0, 0, 0, 0), p1 = make_uint4(0, 0, 0, 0);
            float w0 = 0.f, w1 = 0.f;
            if (j0 < e) {
                int s0 = csr_src[j0];
                p0 = *(const uint4*)(Hb + (size_t)s0 * 64 + l16 * 4);
                w0 = __expf(lrelu(EL[s0 * 4 + h] + erh));
            }
            if (j1 < e) {
                int s1 = csr_src[j1];
                p1 = *(const uint4*)(Hb + (size_t)s1 * 64 + l16 * 4);
                w1 = __expf(lrelu(EL[s1 * 4 + h] + erh));
            }
            sa += w0 + w1;
            acc[0] = fmaf(bflo(p0.x), w0, acc[0]); acc[1] = fmaf(bfhi(p0.x), w0, acc[1]);
            acc[2] = fmaf(bflo(p0.y), w0, acc[2]); acc[3] = fmaf(bfhi(p0.y), w0, acc[3]);
            acc[4] = fmaf(bflo(p0.z), w0, acc[4]); acc[5] = fmaf(bfhi(p0.z), w0, acc[5]);
            acc[6] = fmaf(bflo(p0.w), w0, acc[6]); acc[7] = fmaf(bfhi(p0.w), w0, acc[7]);
            acc[0] = fmaf(bflo(p1.x), w1, acc[0]); acc[1] = fmaf(bfhi(p1.x), w1, acc[1]);
            acc[2] = fmaf(bflo(p1.y), w1, acc[2]); acc[3] = fmaf(bfhi(p1.y), w1, acc[3]);
            acc[4] = fmaf(bflo(p1.z), w1, acc[4]); acc[5] = fmaf(bfhi(p1.z), w1, acc[5]);
            acc[6] = fmaf(bflo(p1.w), w1, acc[6]); acc[7] = fmaf(bfhi(p1.w), w1, acc[7]);
        }

        #pragma unroll
        for (int c = 0; c < 8; c++) {
            acc[c] += __shfl_xor(acc[c], 16);
            acc[c] += __shfl_xor(acc[c], 32);
        }
        sa += __shfl_xor(sa, 16);
        sa += __shfl_xor(sa, 32);
        float inv = (e > s) ? 1.f / sa : 0.f;

        float r[8];
        #pragma unroll
        for (int c = 0; c < 8; c++) r[c] = acc[c] * inv + bv[c];

        if (!final_layer) {
            if (g == 0) {
                uint4 pk;
                pk.x = bfpack(fmaxf(r[0], 0.f), fmaxf(r[1], 0.f));
                pk.y = bfpack(fmaxf(r[2], 0.f), fmaxf(r[3], 0.f));
                pk.z = bfpack(fmaxf(r[4], 0.f), fmaxf(r[5], 0.f));
                pk.w = bfpack(fmaxf(r[6], 0.f), fmaxf(r[7], 0.f));
                *(uint4*)((unsigned*)out + (size_t)n * 64 + l16 * 4) = pk;
            }
        } else {
            #pragma unroll
            for (int c = 0; c < 8; c++) {
                r[c] += __shfl_xor(r[c], 4);
                r[c] += __shfl_xor(r[c], 8);
            }
            if (g == 0 && l16 < 4) {
                float* po = (float*)out + (size_t)n * 32 + l16 * 8;
                *(float4*)po = make_float4(0.25f * r[0], 0.25f * r[1], 0.25f * r[2], 0.25f * r[3]);
                *(float4*)(po + 4) = make_float4(0.25f * r[4], 0.25f * r[5], 0.25f * r[6], 0.25f * r[7]);
            }
        }
    }
}

extern "C" void kernel_launch(void* const* d_in, const int* in_sizes, int n_in,
                              void* d_out, int out_size, void* d_ws, size_t ws_size,
                              hipStream_t stream) {
    const float* feat = (const float*)d_in[0];
    const int* src = (const int*)d_in[1];
    const int* dst = (const int*)d_in[2];
    const float* W1 = (const float*)d_in[3];
    const float* al1 = (const float*)d_in[4];
    const float* ar1 = (const float*)d_in[5];
    const float* b1 = (const float*)d_in[6];
    const float* W2 = (const float*)d_in[7];
    const float* al2 = (const float*)d_in[8];
    const float* ar2 = (const float*)d_in[9];
    const float* b2 = (const float*)d_in[10];
    float* out = (float*)d_out;

    char* ws = (char*)d_ws;
    size_t off = 0;
    auto alloc = [&](size_t bytes) {
        void* p = ws + off;
        off += (bytes + 255) & ~(size_t)255;
        return p;
    };
    int* deg = (int*)alloc((size_t)N_NODES * 4);
    int* done = (int*)alloc(256);
    int* rs = (int*)alloc(((size_t)N_NODES + 1) * 4);
    int* bsums = (int*)alloc(128 * 4);
    unsigned short* rank = (unsigned short*)alloc((size_t)HIST4_BLOCKS * 1024 * 2); // 1.6 MB
    int* csr_src = (int*)alloc((size_t)N_EDGES * 4);
    unsigned* Hb = (unsigned*)alloc((size_t)N_NODES * 64 * 4);     // bf16 H pairs
    float* el = (float*)alloc((size_t)N_NODES * 4 * 4);
    float* er = (float*)alloc((size_t)N_NODES * 4 * 4);
    unsigned* out1b = (unsigned*)alloc((size_t)N_NODES * 64 * 4);  // bf16 relu(out1)
    unsigned short* wt1 = (unsigned short*)alloc(128 * 128 * 2);
    unsigned short* wt2 = (unsigned short*)alloc(128 * 128 * 2);
    unsigned short* et1 = (unsigned short*)alloc(16 * 128 * 2);
    unsigned short* et2 = (unsigned short*)alloc(16 * 128 * 2);

    int gat_blocks = (N_NODES + 15) / 16;

    // K1: wprep + E + zero deg/done
    k_prep0<<<229, 256, 0, stream>>>(W1, al1, ar1, W2, al2, ar2,
                                     wt1, wt2, et1, et2, deg, done);
    // K2: layer-1 GEMM co-scheduled with rank-histogram (one atomic pass total for CSR build)
    k_gemm_hist<<<GEMM_BLOCKS + HIST4_BLOCKS, 256, 0, stream>>>(feat, wt1, et1, Hb, el, er,
                                                                dst, deg, rank);
    // K3: scan + atomic-free scatter
    k_scan_scatter<<<SCAN_BLOCKS, 256, 0, stream>>>(deg, rs, bsums, done,
                                                    src, dst, rank, csr_src);
    // K4: gather layer 1
    k_gather<<<gat_blocks, 256, 0, stream>>>(rs, csr_src, el, er, Hb, b1, out1b, 0);
    // K5: gemm layer 2   K6: gather layer 2
    k_gemm<<<GEMM_BLOCKS, 256, 0, stream>>>(out1b, wt2, et2, Hb, el, er, 1);
    k_gather<<<gat_blocks, 256, 0, stream>>>(rs, csr_src, el, er, Hb, b2, out, 1);
}

// Round 7
// 290.799 us; speedup vs baseline: 1.3001x; 1.0685x over previous
//
#include <hip/hip_runtime.h>
#include <math.h>

#define N_NODES 100000
#define N_EDGES 800000
#define NEG_SLOPE 0.2f
#define GEMM_BLOCKS 782            // ceil(100000/128)
#define HIST4_BLOCKS 782           // ceil(800000/1024), 4 edges/thread
#define HIST_BLOCKS 3125           // 800000/256
#define SCAN_BLOCKS 98

typedef __attribute__((ext_vector_type(8))) short short8;
typedef __attribute__((ext_vector_type(4))) float floatx4;

__device__ __forceinline__ float lrelu(float x) { return x > 0.f ? x : NEG_SLOPE * x; }

__device__ __forceinline__ unsigned bf16_rne(float f) {
    unsigned u = __float_as_uint(f);
    return (u + 0x7fffu + ((u >> 16) & 1u)) >> 16;
}
__device__ __forceinline__ unsigned bfpack(float lo, float hi) {
    return bf16_rne(lo) | (bf16_rne(hi) << 16);
}
__device__ __forceinline__ float bflo(unsigned p) { return __uint_as_float(p << 16); }
__device__ __forceinline__ float bfhi(unsigned p) { return __uint_as_float(p & 0xffff0000u); }

// ---------------- K1: W^T (0..127) + E (128..129) + zero deg (130..227) + zero done (228) ----------------
__global__ __launch_bounds__(256) void k_prep0(const float* __restrict__ W1,
                                               const float* __restrict__ al1,
                                               const float* __restrict__ ar1,
                                               const float* __restrict__ W2,
                                               const float* __restrict__ al2,
                                               const float* __restrict__ ar2,
                                               unsigned short* __restrict__ wt1,
                                               unsigned short* __restrict__ wt2,
                                               unsigned short* __restrict__ et1,
                                               unsigned short* __restrict__ et2,
                                               int* __restrict__ deg,
                                               int* __restrict__ done) {
    int b = blockIdx.x, tid = threadIdx.x;
    if (b < 128) {
        int t2 = b * 256 + tid;                   // 0..32767
        const float* W = (t2 < 16384) ? W1 : W2;
        unsigned short* wt = (t2 < 16384) ? wt1 : wt2;
        int t = t2 & 16383;
        int n = t >> 7, k = t & 127;
        wt[t] = (unsigned short)bf16_rne(W[k * 128 + n]);
    } else if (b < 130) {
        // E[n][k]: n<4 -> (W al)_head n ; 4<=n<8 -> (W ar)_head n-4 ; else 0
        const float* W = (b == 128) ? W1 : W2;
        const float* al = (b == 128) ? al1 : al2;
        const float* ar = (b == 128) ? ar1 : ar2;
        unsigned short* et = (b == 128) ? et1 : et2;
        for (int o = tid * 8; o < tid * 8 + 8; o++) {   // 2048 outputs
            int n = o >> 7, k = o & 127;
            float sacc = 0.f;
            if (n < 8) {
                const float* a = (n < 4) ? al : ar;
                int hh = n & 3;
                #pragma unroll 8
                for (int c = 0; c < 32; c++)
                    sacc += W[k * 128 + hh * 32 + c] * a[hh * 32 + c];
            }
            et[n * 128 + k] = (unsigned short)bf16_rne(sacc);
        }
    } else if (b < 228) {
        int i = (b - 130) * 1024 + tid * 4;
        if (i + 3 < N_NODES) *(int4*)&deg[i] = make_int4(0, 0, 0, 0);
        else { for (int j = i; j < N_NODES; j++) if (j >= 0) deg[j] = 0; }
    } else {
        if (tid < 64) done[tid] = 0;
    }
}

// ---------------- shared GEMM tile body (MFMA, direct-global A frags, el/er via MFMA) ----------------
__device__ __forceinline__ void gemm_tile(int base, const void* __restrict__ Xv,
                                          const unsigned short* __restrict__ wt,
                                          const unsigned short* __restrict__ et,
                                          unsigned* __restrict__ Hb,
                                          float* __restrict__ EL,
                                          float* __restrict__ ER,
                                          int src_bf16,
                                          unsigned short* wsh,   // [128*128]
                                          unsigned short* esh) { // [16*136]
    int tid = threadIdx.x;
    int w = tid >> 6, lane = tid & 63;
    int q = lane >> 4, nl = lane & 15;

    const uint4* wt4 = (const uint4*)wt;
    #pragma unroll
    for (int i = 0; i < 8; i++) {
        int idx = tid + i * 256;                // 0..2047 chunks of 8 shorts
        int rn = idx >> 4, c8 = idx & 15;
        int kc = c8 >> 2, qq = c8 & 3;
        int slot = rn * 128 + ((kc ^ ((rn >> 2) & 3)) * 4 + (qq ^ (rn & 3))) * 8;
        *(uint4*)&wsh[slot] = wt4[idx];
    }
    {
        const uint4* et4 = (const uint4*)et;
        int rn = tid >> 4, c8 = tid & 15;
        *(uint4*)&esh[rn * 136 + c8 * 8] = et4[tid];
    }

    short8 afr[2][4];
    int row0 = base + w * 32 + nl;
    if (!src_bf16) {
        const float4* X4 = (const float4*)Xv;
        #pragma unroll
        for (int rt = 0; rt < 2; rt++) {
            int rr = row0 + rt * 16; if (rr > N_NODES - 1) rr = N_NODES - 1;
            const float4* px = X4 + (size_t)rr * 32 + q * 2;
            #pragma unroll
            for (int kc = 0; kc < 4; kc++) {
                float4 u = px[kc * 8], v = px[kc * 8 + 1];
                short8 f;
                f[0] = (short)bf16_rne(u.x); f[1] = (short)bf16_rne(u.y);
                f[2] = (short)bf16_rne(u.z); f[3] = (short)bf16_rne(u.w);
                f[4] = (short)bf16_rne(v.x); f[5] = (short)bf16_rne(v.y);
                f[6] = (short)bf16_rne(v.z); f[7] = (short)bf16_rne(v.w);
                afr[rt][kc] = f;
            }
        }
    } else {
        const unsigned short* Xb = (const unsigned short*)Xv;
        #pragma unroll
        for (int rt = 0; rt < 2; rt++) {
            int rr = row0 + rt * 16; if (rr > N_NODES - 1) rr = N_NODES - 1;
            #pragma unroll
            for (int kc = 0; kc < 4; kc++)
                afr[rt][kc] = *(const short8*)(Xb + (size_t)rr * 128 + kc * 32 + q * 8);
        }
    }

    floatx4 acc[2][8];
    floatx4 acc_e[2];
    #pragma unroll
    for (int rt = 0; rt < 2; rt++) {
        acc_e[rt] = (floatx4){0.f, 0.f, 0.f, 0.f};
        #pragma unroll
        for (int ct = 0; ct < 8; ct++)
            acc[rt][ct] = (floatx4){0.f, 0.f, 0.f, 0.f};
    }

    __syncthreads();

    int sw_hi = (nl >> 2) & 3, sw_lo = nl & 3;
    #pragma unroll
    for (int ct = 0; ct < 8; ct++) {
        int rbase = (ct * 16 + nl) * 128;
        #pragma unroll
        for (int kc = 0; kc < 4; kc++) {
            short8 b = *(const short8*)&wsh[rbase + ((kc ^ sw_hi) * 4 + (q ^ sw_lo)) * 8];
            acc[0][ct] = __builtin_amdgcn_mfma_f32_16x16x32_bf16(afr[0][kc], b, acc[0][ct], 0, 0, 0);
            acc[1][ct] = __builtin_amdgcn_mfma_f32_16x16x32_bf16(afr[1][kc], b, acc[1][ct], 0, 0, 0);
        }
    }
    #pragma unroll
    for (int kc = 0; kc < 4; kc++) {
        short8 e8 = *(const short8*)&esh[nl * 136 + (kc * 4 + q) * 8];
        acc_e[0] = __builtin_amdgcn_mfma_f32_16x16x32_bf16(afr[0][kc], e8, acc_e[0], 0, 0, 0);
        acc_e[1] = __builtin_amdgcn_mfma_f32_16x16x32_bf16(afr[1][kc], e8, acc_e[1], 0, 0, 0);
    }

    #pragma unroll
    for (int rt = 0; rt < 2; rt++) {
        #pragma unroll
        for (int r = 0; r < 4; r++) {
            int row = base + w * 32 + rt * 16 + q * 4 + r;
            bool valid = row < N_NODES;
            unsigned* hrow = Hb + (size_t)row * 64;
            #pragma unroll
            for (int ct = 0; ct < 8; ct++) {
                float vlo = acc[rt][ct][r];
                float vhi = __shfl_down(vlo, 1);
                if (valid && !(nl & 1)) hrow[ct * 8 + (nl >> 1)] = bfpack(vlo, vhi);
            }
            if (valid && nl < 8) {
                float v = acc_e[rt][r];
                if (nl < 4) EL[row * 4 + nl] = v;
                else        ER[row * 4 + (nl & 3)] = v;
            }
        }
    }
}

// ---------------- K2: gemm layer-1 (blocks 0..781) + rank-histogram (782..1563) ----------------
__global__ __launch_bounds__(256) void k_gemm_hist(const float* __restrict__ feat,
                                                   const unsigned short* __restrict__ wt1,
                                                   const unsigned short* __restrict__ et1,
                                                   unsigned* __restrict__ Hb,
                                                   float* __restrict__ EL,
                                                   float* __restrict__ ER,
                                                   const int* __restrict__ dst,
                                                   int* __restrict__ deg,
                                                   unsigned short* __restrict__ rank) {
    __shared__ unsigned short wsh[128 * 128];
    __shared__ unsigned short esh[16 * 136];
    int b = blockIdx.x;
    if (b < GEMM_BLOCKS) {
        gemm_tile(b * 128, feat, wt1, et1, Hb, EL, ER, 0, wsh, esh);
    } else {
        int ebase = (b - GEMM_BLOCKS) * 1024 + threadIdx.x;
        int d[4], c[4];
        #pragma unroll
        for (int k = 0; k < 4; k++) {
            int e = ebase + k * 256;
            d[k] = (e < N_EDGES) ? dst[e] : 0;
        }
        #pragma unroll
        for (int k = 0; k < 4; k++) {
            int e = ebase + k * 256;
            c[k] = (e < N_EDGES) ? atomicAdd(&deg[d[k]], 1) : 0;
        }
        #pragma unroll
        for (int k = 0; k < 4; k++) {
            int e = ebase + k * 256;
            if (e < N_EDGES) rank[e] = (unsigned short)c[k];
        }
    }
}

// ---------------- K6: plain gemm (layer 2) ----------------
__global__ __launch_bounds__(256) void k_gemm(const void* __restrict__ Xv,
                                              const unsigned short* __restrict__ wt,
                                              const unsigned short* __restrict__ et,
                                              unsigned* __restrict__ Hb,
                                              float* __restrict__ EL,
                                              float* __restrict__ ER,
                                              int src_bf16) {
    __shared__ unsigned short wsh[128 * 128];
    __shared__ unsigned short esh[16 * 136];
    gemm_tile(blockIdx.x * 128, Xv, wt, et, Hb, EL, ER, src_bf16, wsh, esh);
}

// ---------------- K3: exclusive scan over deg (98 blocks, one spin-sync; rs only) ----------------
__global__ __launch_bounds__(256) void k_scan(const int* __restrict__ deg,
                                              int* __restrict__ rs,
                                              int* __restrict__ bsums,
                                              int* __restrict__ done) {
    __shared__ int sd[256];
    int tid = threadIdx.x, b = blockIdx.x;
    int base = b * 1024 + tid * 4;
    int v0 = (base + 0 < N_NODES) ? deg[base + 0] : 0;
    int v1 = (base + 1 < N_NODES) ? deg[base + 1] : 0;
    int v2 = (base + 2 < N_NODES) ? deg[base + 2] : 0;
    int v3 = (base + 3 < N_NODES) ? deg[base + 3] : 0;
    int t = v0 + v1 + v2 + v3;
    sd[tid] = t;
    __syncthreads();
    int incl = t;
    for (int off = 1; off < 256; off <<= 1) {
        int x = (tid >= off) ? sd[tid - off] : 0;
        __syncthreads();
        incl += x;
        sd[tid] = incl;
        __syncthreads();
    }
    int excl = incl - t;

    if (tid == 255) {
        atomicExch(&bsums[b], incl);
        __threadfence();
        atomicAdd(&done[0], 1);
    }
    if (tid == 0) {
        while (atomicAdd(&done[0], 0) < SCAN_BLOCKS) { }
    }
    __syncthreads();

    int bv = (tid < b) ? atomicAdd(&bsums[tid], 0) : 0;
    __syncthreads();
    sd[tid] = bv;
    __syncthreads();
    for (int off = 128; off > 0; off >>= 1) {
        if (tid < off) sd[tid] += sd[tid + off];
        __syncthreads();
    }
    int boff = sd[0];

    int p0 = excl + boff;
    if (base + 0 < N_NODES) rs[base + 0] = p0;
    if (base + 1 < N_NODES) rs[base + 1] = p0 + v0;
    if (base + 2 < N_NODES) rs[base + 2] = p0 + v0 + v1;
    if (base + 3 < N_NODES) rs[base + 3] = p0 + v0 + v1 + v2;
    if (b == 0 && tid == 0) rs[N_NODES] = N_EDGES;
}

// ---------------- K4: atomic-free scatter (full grid, pure BW) ----------------
__global__ void k_scatter_free(const int* __restrict__ src, const int* __restrict__ dst,
                               const unsigned short* __restrict__ rank,
                               const int* __restrict__ rs, int* __restrict__ csr_src) {
    int e = blockIdx.x * blockDim.x + threadIdx.x;
    if (e < N_EDGES) {
        csr_src[rs[dst[e]] + rank[e]] = src[e];
    }
}

// ---------------- K5/K7: gather (baseline-proven: 4 nodes serial per wave, 8-edge g-split) ----------------
__global__ __launch_bounds__(256) void k_gather(const int* __restrict__ rs,
                                                const int* __restrict__ csr_src,
                                                const float* __restrict__ EL,
                                                const float* __restrict__ ER,
                                                const unsigned* __restrict__ Hb,
                                                const float* __restrict__ bias,
                                                void* __restrict__ out,
                                                int final_layer) {
    int wid = (blockIdx.x * blockDim.x + threadIdx.x) >> 6;
    int lane = threadIdx.x & 63;
    int g = lane >> 4, l16 = lane & 15;
    int h = l16 >> 2;
    int n0 = wid * 4;
    if (n0 >= N_NODES) return;
    int nend = min(n0 + 4, N_NODES);

    float bv[8];
    #pragma unroll
    for (int c = 0; c < 8; c++) bv[c] = bias[l16 * 8 + c];

    for (int n = n0; n < nend; n++) {
        int s = rs[n], e = rs[n + 1];
        float erh = ER[n * 4 + h];
        float acc[8];
        #pragma unroll
        for (int c = 0; c < 8; c++) acc[c] = 0.f;
        float sa = 0.f;

        for (int j = s; j < e; j += 8) {
            int j0 = j + g, j1 = j + 4 + g;
            uint4 p0 = make_uint4(0, 0, 0, 0), p1 = make_uint4(0, 0, 0, 0);
            float w0 = 0.f, w1 = 0.f;
            if (j0 < e) {
                int s0 = csr_src[j0];
                p0 = *(const uint4*)(Hb + (size_t)s0 * 64 + l16 * 4);
                w0 = __expf(lrelu(EL[s0 * 4 + h] + erh));
            }
            if (j1 < e) {
                int s1 = csr_src[j1];
                p1 = *(const uint4*)(Hb + (size_t)s1 * 64 + l16 * 4);
                w1 = __expf(lrelu(EL[s1 * 4 + h] + erh));
            }
            sa += w0 + w1;
            acc[0] = fmaf(bflo(p0.x), w0, acc[0]); acc[1] = fmaf(bfhi(p0.x), w0, acc[1]);
            acc[2] = fmaf(bflo(p0.y), w0, acc[2]); acc[3] = fmaf(bfhi(p0.y), w0, acc[3]);
            acc[4] = fmaf(bflo(p0.z), w0, acc[4]); acc[5] = fmaf(bfhi(p0.z), w0, acc[5]);
            acc[6] = fmaf(bflo(p0.w), w0, acc[6]); acc[7] = fmaf(bfhi(p0.w), w0, acc[7]);
            acc[0] = fmaf(bflo(p1.x), w1, acc[0]); acc[1] = fmaf(bfhi(p1.x), w1, acc[1]);
            acc[2] = fmaf(bflo(p1.y), w1, acc[2]); acc[3] = fmaf(bfhi(p1.y), w1, acc[3]);
            acc[4] = fmaf(bflo(p1.z), w1, acc[4]); acc[5] = fmaf(bfhi(p1.z), w1, acc[5]);
            acc[6] = fmaf(bflo(p1.w), w1, acc[6]); acc[7] = fmaf(bfhi(p1.w), w1, acc[7]);
        }

        #pragma unroll
        for (int c = 0; c < 8; c++) {
            acc[c] += __shfl_xor(acc[c], 16);
            acc[c] += __shfl_xor(acc[c], 32);
        }
        sa += __shfl_xor(sa, 16);
        sa += __shfl_xor(sa, 32);
        float inv = (e > s) ? 1.f / sa : 0.f;

        float r[8];
        #pragma unroll
        for (int c = 0; c < 8; c++) r[c] = acc[c] * inv + bv[c];

        if (!final_layer) {
            if (g == 0) {
                uint4 pk;
                pk.x = bfpack(fmaxf(r[0], 0.f), fmaxf(r[1], 0.f));
                pk.y = bfpack(fmaxf(r[2], 0.f), fmaxf(r[3], 0.f));
                pk.z = bfpack(fmaxf(r[4], 0.f), fmaxf(r[5], 0.f));
                pk.w = bfpack(fmaxf(r[6], 0.f), fmaxf(r[7], 0.f));
                *(uint4*)((unsigned*)out + (size_t)n * 64 + l16 * 4) = pk;
            }
        } else {
            #pragma unroll
            for (int c = 0; c < 8; c++) {
                r[c] += __shfl_xor(r[c], 4);
                r[c] += __shfl_xor(r[c], 8);
            }
            if (g == 0 && l16 < 4) {
                float* po = (float*)out + (size_t)n * 32 + l16 * 8;
                *(float4*)po = make_float4(0.25f * r[0], 0.25f * r[1], 0.25f * r[2], 0.25f * r[3]);
                *(float4*)(po + 4) = make_float4(0.25f * r[4], 0.25f * r[5], 0.25f * r[6], 0.25f * r[7]);
            }
        }
    }
}

extern "C" void kernel_launch(void* const* d_in, const int* in_sizes, int n_in,
                              void* d_out, int out_size, void* d_ws, size_t ws_size,
                              hipStream_t stream) {
    const float* feat = (const float*)d_in[0];
    const int* src = (const int*)d_in[1];
    const int* dst = (const int*)d_in[2];
    const float* W1 = (const float*)d_in[3];
    const float* al1 = (const float*)d_in[4];
    const float* ar1 = (const float*)d_in[5];
    const float* b1 = (const float*)d_in[6];
    const float* W2 = (const float*)d_in[7];
    const float* al2 = (const float*)d_in[8];
    const float* ar2 = (const float*)d_in[9];
    const float* b2 = (const float*)d_in[10];
    float* out = (float*)d_out;

    char* ws = (char*)d_ws;
    size_t off = 0;
    auto alloc = [&](size_t bytes) {
        void* p = ws + off;
        off += (bytes + 255) & ~(size_t)255;
        return p;
    };
    int* deg = (int*)alloc((size_t)N_NODES * 4);
    int* done = (int*)alloc(256);
    int* rs = (int*)alloc(((size_t)N_NODES + 1) * 4);
    int* bsums = (int*)alloc(128 * 4);
    unsigned short* rank = (unsigned short*)alloc((size_t)HIST4_BLOCKS * 1024 * 2); // 1.6 MB
    int* csr_src = (int*)alloc((size_t)N_EDGES * 4);
    unsigned* Hb = (unsigned*)alloc((size_t)N_NODES * 64 * 4);     // bf16 H pairs
    float* el = (float*)alloc((size_t)N_NODES * 4 * 4);
    float* er = (float*)alloc((size_t)N_NODES * 4 * 4);
    unsigned* out1b = (unsigned*)alloc((size_t)N_NODES * 64 * 4);  // bf16 relu(out1)
    unsigned short* wt1 = (unsigned short*)alloc(128 * 128 * 2);
    unsigned short* wt2 = (unsigned short*)alloc(128 * 128 * 2);
    unsigned short* et1 = (unsigned short*)alloc(16 * 128 * 2);
    unsigned short* et2 = (unsigned short*)alloc(16 * 128 * 2);

    int gat_blocks = (N_NODES + 15) / 16;

    // K1: wprep + E + zero deg/done
    k_prep0<<<229, 256, 0, stream>>>(W1, al1, ar1, W2, al2, ar2,
                                     wt1, wt2, et1, et2, deg, done);
    // K2: layer-1 GEMM co-scheduled with rank-histogram (single atomic pass for CSR build)
    k_gemm_hist<<<GEMM_BLOCKS + HIST4_BLOCKS, 256, 0, stream>>>(feat, wt1, et1, Hb, el, er,
                                                                dst, deg, rank);
    // K3: scan (rs only)   K4: atomic-free scatter at full parallelism
    k_scan<<<SCAN_BLOCKS, 256, 0, stream>>>(deg, rs, bsums, done);
    k_scatter_free<<<HIST_BLOCKS, 256, 0, stream>>>(src, dst, rank, rs, csr_src);
    // K5: gather layer 1
    k_gather<<<gat_blocks, 256, 0, stream>>>(rs, csr_src, el, er, Hb, b1, out1b, 0);
    // K6: gemm layer 2   K7: gather layer 2
    k_gemm<<<GEMM_BLOCKS, 256, 0, stream>>>(out1b, wt2, et2, Hb, el, er, 1);
    k_gather<<<gat_blocks, 256, 0, stream>>>(rs, csr_src, el, er, Hb, b2, out, 1);
}